// Round 2
// baseline (537.581 us; speedup 1.0000x reference)
//
#include <hip/hip_runtime.h>
#include <stdint.h>
#include <math.h>

// Problem constants
#define Bb 4
#define Tt 2048
#define Cc 1024
#define Hh 16
#define Dd 64
#define Mm (Bb * Tt)   // 8192 rows

typedef __attribute__((ext_vector_type(8))) short bf8;     // 8 x bf16 (4 VGPRs), MFMA A/B frag
typedef __attribute__((ext_vector_type(4))) float f32x4;   // MFMA C/D frag
typedef __attribute__((ext_vector_type(8))) unsigned short u16x8;

__device__ __forceinline__ unsigned short f2bf(float f) {
  union { float f; unsigned u; } v; v.f = f;
  unsigned r = v.u + 0x7fffu + ((v.u >> 16) & 1u);   // RNE
  return (unsigned short)(r >> 16);
}
__device__ __forceinline__ float bf2f(unsigned short s) {
  union { unsigned u; float f; } v; v.u = ((unsigned)s) << 16;
  return v.f;
}
__device__ __forceinline__ void gl_lds16(const void* g, void* l) {
  __builtin_amdgcn_global_load_lds(
      (const __attribute__((address_space(1))) void*)g,
      (__attribute__((address_space(3))) void*)l, 16, 0, 0);
}

// ---------------- fp32 -> bf16 cast, 8 elems/thread -------------------------
__global__ __launch_bounds__(256) void cast_f32_bf16(
    const float* __restrict__ in, unsigned short* __restrict__ out, int n) {
  int i = (blockIdx.x * 256 + threadIdx.x) * 8;
  if (i >= n) return;
  const float4* p = (const float4*)(in + i);
  float4 a = p[0], b = p[1];
  u16x8 o;
  o[0] = f2bf(a.x); o[1] = f2bf(a.y); o[2] = f2bf(a.z); o[3] = f2bf(a.w);
  o[4] = f2bf(b.x); o[5] = f2bf(b.y); o[6] = f2bf(b.z); o[7] = f2bf(b.w);
  *(u16x8*)(out + i) = o;
}

// ---------------- bt-GEMM: C[M,N] = A[M,K] @ Bw[N,K]^T ----------------------
// m97 structure: 128x128 tile, BK=32, 4 waves each owning 64x64 (4x4 frags of
// 16x16x32 bf16 MFMA), global_load_lds width-16 staging, single LDS buffer.
template <int FP32OUT>
__global__ __launch_bounds__(256, 2)
void gemm_bt(const unsigned short* __restrict__ A,
             const unsigned short* __restrict__ Bw,
             void* __restrict__ Cout,
             const float* __restrict__ bias,
             int M, int N, int K) {
  __shared__ unsigned short As[128 * 32];
  __shared__ unsigned short Bs[128 * 32];
  const int tid = threadIdx.x;
  const int lane = tid & 63;
  const int w = tid >> 6;
  const int wr = w >> 1, wc = w & 1;                 // 2x2 wave grid
  const int row0 = blockIdx.y * 128;
  const int col0 = blockIdx.x * 128;
  const int lr = lane & 15;                          // frag row within 16
  const int lk = (lane >> 4) * 8;                    // frag k offset

  f32x4 acc[4][4] = {};

  // staging: LDS byte offset == tid*16 (wave-uniform base + lane*16, G21)
  const int sr = tid >> 2;          // 0..63 (row within 64-row chunk)
  const int sc = (tid & 3) * 8;     // k-elem offset (16B granules)

  for (int k0 = 0; k0 < K; k0 += 32) {
    gl_lds16(A  + (size_t)(row0 + sr) * K + k0 + sc,      &As[sr * 32 + sc]);
    gl_lds16(A  + (size_t)(row0 + 64 + sr) * K + k0 + sc, &As[(64 + sr) * 32 + sc]);
    gl_lds16(Bw + (size_t)(col0 + sr) * K + k0 + sc,      &Bs[sr * 32 + sc]);
    gl_lds16(Bw + (size_t)(col0 + 64 + sr) * K + k0 + sc, &Bs[(64 + sr) * 32 + sc]);
    __syncthreads();   // compiler drains vmcnt before barrier

    bf8 a[4], b[4];
#pragma unroll
    for (int mi = 0; mi < 4; ++mi)
      a[mi] = *(const bf8*)&As[(wr * 64 + mi * 16 + lr) * 32 + lk];
#pragma unroll
    for (int ni = 0; ni < 4; ++ni)
      b[ni] = *(const bf8*)&Bs[(wc * 64 + ni * 16 + lr) * 32 + lk];
#pragma unroll
    for (int mi = 0; mi < 4; ++mi)
#pragma unroll
      for (int ni = 0; ni < 4; ++ni)
        acc[mi][ni] = __builtin_amdgcn_mfma_f32_16x16x32_bf16(
            a[mi], b[ni], acc[mi][ni], 0, 0, 0);
    __syncthreads();
  }

  // epilogue: C/D layout col=lane&15, row=(lane>>4)*4+r  [measured m89/m91]
#pragma unroll
  for (int mi = 0; mi < 4; ++mi) {
#pragma unroll
    for (int ni = 0; ni < 4; ++ni) {
      const int col = col0 + wc * 64 + ni * 16 + lr;
#pragma unroll
      for (int r = 0; r < 4; ++r) {
        const int row = row0 + wr * 64 + mi * 16 + (lane >> 4) * 4 + r;
        if (FP32OUT) {
          ((float*)Cout)[(size_t)row * N + col] = acc[mi][ni][r] + bias[col];
        } else {
          ((unsigned short*)Cout)[(size_t)row * N + col] = f2bf(acc[mi][ni][r]);
        }
      }
    }
  }
}

// ---------------- flash attention ------------------------------------------
// Q,K,V,O in [B,T,C] layout, head h at columns h*64..h*64+63, row stride C.
// Block: 4 waves; each wave owns 16 q rows (QBLK=64/block). KV tile = 32 rows.
__global__ __launch_bounds__(256, 2)
void flash_attn(const unsigned short* __restrict__ Q,
                const unsigned short* __restrict__ Km,
                const unsigned short* __restrict__ V,
                unsigned short* __restrict__ O) {
  __shared__ unsigned short Ks[32 * 64];
  __shared__ unsigned short Vs[32 * 64];
  __shared__ unsigned short Ps[4][16 * 32];   // per-wave P repack buffer

  const int tid = threadIdx.x;
  const int lane = tid & 63;
  const int w = tid >> 6;
  const int bh = blockIdx.x;                  // 0..63
  const int qt = blockIdx.y;                  // 0..31
  const int b = bh >> 4, h = bh & 15;
  const size_t base = (size_t)b * Tt * Cc + (size_t)h * Dd;
  const int lr = lane & 15, lg = lane >> 4, lk = lg * 8;
  const int qrow0 = qt * 64 + w * 16;         // wave's first q row

  // Q fragments, pre-scaled by 1/sqrt(D)=0.125 (exact power of 2)
  bf8 qa[2];
#pragma unroll
  for (int kk = 0; kk < 2; ++kk) {
    bf8 t = *(const bf8*)(Q + base + (size_t)(qrow0 + lr) * Cc + kk * 32 + lk);
#pragma unroll
    for (int i = 0; i < 8; ++i)
      qa[kk][i] = (short)f2bf(bf2f((unsigned short)t[i]) * 0.125f);
  }

  float m_r[4], l_r[4];
  f32x4 o_acc[4] = {};
#pragma unroll
  for (int r = 0; r < 4; ++r) { m_r[r] = -INFINITY; l_r[r] = 0.f; }

  // staging map: LDS byte offset = tid*16
  const int vr = tid >> 3;          // 0..31  kv row
  const int vc = (tid & 7) * 8;     // d-elem offset

  for (int kb = 0; kb < Tt; kb += 32) {
    gl_lds16(Km + base + (size_t)(kb + vr) * Cc + vc, &Ks[vr * 64 + vc]);
    gl_lds16(V  + base + (size_t)(kb + vr) * Cc + vc, &Vs[vr * 64 + vc]);
    __syncthreads();

    // S tile [16 q][32 kv]: 2 n-tiles x (K=64 via 2 chained MFMA)
    f32x4 s[2];
#pragma unroll
    for (int nt = 0; nt < 2; ++nt) {
      bf8 k0 = *(const bf8*)&Ks[(nt * 16 + lr) * 64 + lk];
      bf8 k1 = *(const bf8*)&Ks[(nt * 16 + lr) * 64 + 32 + lk];
      f32x4 z = {};
      z = __builtin_amdgcn_mfma_f32_16x16x32_bf16(qa[0], k0, z, 0, 0, 0);
      z = __builtin_amdgcn_mfma_f32_16x16x32_bf16(qa[1], k1, z, 0, 0, 0);
      s[nt] = z;
    }

    // online softmax; lane's rows are lg*4+r, cols nt*16+lr
    float mt[4];
#pragma unroll
    for (int r = 0; r < 4; ++r) mt[r] = fmaxf(s[0][r], s[1][r]);
#pragma unroll
    for (int mask = 1; mask < 16; mask <<= 1)
#pragma unroll
      for (int r = 0; r < 4; ++r) mt[r] = fmaxf(mt[r], __shfl_xor(mt[r], mask));

    float alpha[4];
#pragma unroll
    for (int r = 0; r < 4; ++r) {
      float mn = fmaxf(m_r[r], mt[r]);
      alpha[r] = __expf(m_r[r] - mn);   // 0 on first tile (m_r = -inf)
      m_r[r] = mn;
    }

    float psum[4] = {0.f, 0.f, 0.f, 0.f};
    unsigned short pb[8];
#pragma unroll
    for (int nt = 0; nt < 2; ++nt)
#pragma unroll
      for (int r = 0; r < 4; ++r) {
        float p = __expf(s[nt][r] - m_r[r]);
        psum[r] += p;
        pb[nt * 4 + r] = f2bf(p);
      }
#pragma unroll
    for (int mask = 1; mask < 16; mask <<= 1)
#pragma unroll
      for (int r = 0; r < 4; ++r) psum[r] += __shfl_xor(psum[r], mask);
#pragma unroll
    for (int r = 0; r < 4; ++r) l_r[r] = l_r[r] * alpha[r] + psum[r];
#pragma unroll
    for (int dt = 0; dt < 4; ++dt)
#pragma unroll
      for (int r = 0; r < 4; ++r) o_acc[dt][r] *= alpha[r];

    // repack P (C layout) -> A layout through per-wave LDS
#pragma unroll
    for (int nt = 0; nt < 2; ++nt)
#pragma unroll
      for (int r = 0; r < 4; ++r)
        Ps[w][(lg * 4 + r) * 32 + nt * 16 + lr] = pb[nt * 4 + r];
    asm volatile("s_waitcnt lgkmcnt(0)" ::: "memory");
    bf8 pa = *(const bf8*)&Ps[w][lr * 32 + lk];

    // PV: O[16 q][64 d] += P[16][32] @ V[32][64]; V frag = scalar strided reads
#pragma unroll
    for (int dt = 0; dt < 4; ++dt) {
      bf8 vb;
#pragma unroll
      for (int i = 0; i < 8; ++i)
        vb[i] = (short)Vs[(lk + i) * 64 + dt * 16 + lr];
      o_acc[dt] = __builtin_amdgcn_mfma_f32_16x16x32_bf16(pa, vb, o_acc[dt], 0, 0, 0);
    }
    __syncthreads();
  }

  // epilogue: normalize and store
#pragma unroll
  for (int dt = 0; dt < 4; ++dt)
#pragma unroll
    for (int r = 0; r < 4; ++r) {
      float v = o_acc[dt][r] / l_r[r];
      O[base + (size_t)(qrow0 + lg * 4 + r) * Cc + dt * 16 + lr] = f2bf(v);
    }
}

// ---------------- host launcher --------------------------------------------
extern "C" void kernel_launch(void* const* d_in, const int* in_sizes, int n_in,
                              void* d_out, int out_size, void* d_ws, size_t ws_size,
                              hipStream_t stream) {
  (void)in_sizes; (void)n_in; (void)out_size; (void)ws_size;
  const float* hs = (const float*)d_in[0];
  const float* wq = (const float*)d_in[1];
  const float* wk = (const float*)d_in[2];
  const float* wv = (const float*)d_in[3];
  const float* wo = (const float*)d_in[4];
  const float* bo = (const float*)d_in[5];

  // workspace layout (bf16), 72 MB total.
  // Xb (bf16 hidden) is dead after the QKV projections, so attention output
  // reuses it — no separate Ob buffer.
  char* ws = (char*)d_ws;
  const size_t MB = 1u << 20;
  unsigned short* Xb  = (unsigned short*)(ws + 0);        // 16 MB (later: attn out)
  unsigned short* Wqb = (unsigned short*)(ws + 16 * MB);  // 2 MB each
  unsigned short* Wkb = (unsigned short*)(ws + 18 * MB);
  unsigned short* Wvb = (unsigned short*)(ws + 20 * MB);
  unsigned short* Wob = (unsigned short*)(ws + 22 * MB);
  unsigned short* Qb  = (unsigned short*)(ws + 24 * MB);  // 16 MB each
  unsigned short* Kb  = (unsigned short*)(ws + 40 * MB);
  unsigned short* Vb  = (unsigned short*)(ws + 56 * MB);
  unsigned short* Ob  = Xb;                               // alias (Xb dead by then)

  cast_f32_bf16<<<(Mm * Cc) / (256 * 8), 256, 0, stream>>>(hs, Xb, Mm * Cc);
  cast_f32_bf16<<<(Cc * Cc) / (256 * 8), 256, 0, stream>>>(wq, Wqb, Cc * Cc);
  cast_f32_bf16<<<(Cc * Cc) / (256 * 8), 256, 0, stream>>>(wk, Wkb, Cc * Cc);
  cast_f32_bf16<<<(Cc * Cc) / (256 * 8), 256, 0, stream>>>(wv, Wvb, Cc * Cc);
  cast_f32_bf16<<<(Cc * Cc) / (256 * 8), 256, 0, stream>>>(wo, Wob, Cc * Cc);

  dim3 gg(Cc / 128, Mm / 128);  // (8, 64)
  gemm_bt<0><<<gg, 256, 0, stream>>>(Xb, Wqb, Qb, nullptr, Mm, Cc, Cc);
  gemm_bt<0><<<gg, 256, 0, stream>>>(Xb, Wkb, Kb, nullptr, Mm, Cc, Cc);
  gemm_bt<0><<<gg, 256, 0, stream>>>(Xb, Wvb, Vb, nullptr, Mm, Cc, Cc);

  flash_attn<<<dim3(Bb * Hh, Tt / 64), 256, 0, stream>>>(Qb, Kb, Vb, Ob);

  gemm_bt<1><<<gg, 256, 0, stream>>>(Ob, Wob, (float*)d_out, bo, Mm, Cc, Cc);
}

// Round 3
// 338.572 us; speedup vs baseline: 1.5878x; 1.5878x over previous
//
#include <hip/hip_runtime.h>
#include <stdint.h>
#include <math.h>

// Problem constants
#define Bb 4
#define Tt 2048
#define Cc 1024
#define Hh 16
#define Dd 64
#define Mm (Bb * Tt)   // 8192 rows
#define KVB 64

typedef __attribute__((ext_vector_type(8))) short bf8;     // 8 x bf16 (4 VGPRs), MFMA A/B frag
typedef __attribute__((ext_vector_type(4))) float f32x4;   // MFMA C/D frag
typedef __attribute__((ext_vector_type(8))) unsigned short u16x8;

__device__ __forceinline__ unsigned short f2bf(float f) {
  union { float f; unsigned u; } v; v.f = f;
  unsigned r = v.u + 0x7fffu + ((v.u >> 16) & 1u);   // RNE
  return (unsigned short)(r >> 16);
}
__device__ __forceinline__ float bf2f(unsigned short s) {
  union { unsigned u; float f; } v; v.u = ((unsigned)s) << 16;
  return v.f;
}
__device__ __forceinline__ void gl_lds16(const void* g, void* l) {
  __builtin_amdgcn_global_load_lds(
      (const __attribute__((address_space(1))) void*)g,
      (__attribute__((address_space(3))) void*)l, 16, 0, 0);
}

// ---------------- fp32 -> bf16 cast, 8 elems/thread -------------------------
__global__ __launch_bounds__(256) void cast_f32_bf16(
    const float* __restrict__ in, unsigned short* __restrict__ out, int n) {
  int i = (blockIdx.x * 256 + threadIdx.x) * 8;
  if (i >= n) return;
  const float4* p = (const float4*)(in + i);
  float4 a = p[0], b = p[1];
  u16x8 o;
  o[0] = f2bf(a.x); o[1] = f2bf(a.y); o[2] = f2bf(a.z); o[3] = f2bf(a.w);
  o[4] = f2bf(b.x); o[5] = f2bf(b.y); o[6] = f2bf(b.z); o[7] = f2bf(b.w);
  *(u16x8*)(out + i) = o;
}

// ---------------- bt-GEMM: C[M,N] = A[M,K] @ Bw[N,K]^T ----------------------
// MODE 0: bf16 row-major out. MODE 1: f32 out + bias. MODE 2: bf16 out in
// transposed attention layout Vt[b*16+h][d][t] (for the V projection).
template <int MODE>
__global__ __launch_bounds__(256, 2)
void gemm_bt(const unsigned short* __restrict__ A,
             const unsigned short* __restrict__ Bw,
             void* __restrict__ Cout,
             const float* __restrict__ bias,
             int M, int N, int K) {
  __shared__ unsigned short As[128 * 32];
  __shared__ unsigned short Bs[128 * 32];
  const int tid = threadIdx.x;
  const int lane = tid & 63;
  const int w = tid >> 6;
  const int wr = w >> 1, wc = w & 1;                 // 2x2 wave grid
  const int row0 = blockIdx.y * 128;
  const int col0 = blockIdx.x * 128;
  const int lr = lane & 15;                          // frag row within 16
  const int lk = (lane >> 4) * 8;                    // frag k offset

  f32x4 acc[4][4] = {};

  const int sr = tid >> 2;          // 0..63 (row within 64-row chunk)
  const int sc = (tid & 3) * 8;     // k-elem offset (16B granules)

  for (int k0 = 0; k0 < K; k0 += 32) {
    gl_lds16(A  + (size_t)(row0 + sr) * K + k0 + sc,      &As[sr * 32 + sc]);
    gl_lds16(A  + (size_t)(row0 + 64 + sr) * K + k0 + sc, &As[(64 + sr) * 32 + sc]);
    gl_lds16(Bw + (size_t)(col0 + sr) * K + k0 + sc,      &Bs[sr * 32 + sc]);
    gl_lds16(Bw + (size_t)(col0 + 64 + sr) * K + k0 + sc, &Bs[(64 + sr) * 32 + sc]);
    __syncthreads();

    bf8 a[4], b[4];
#pragma unroll
    for (int mi = 0; mi < 4; ++mi)
      a[mi] = *(const bf8*)&As[(wr * 64 + mi * 16 + lr) * 32 + lk];
#pragma unroll
    for (int ni = 0; ni < 4; ++ni)
      b[ni] = *(const bf8*)&Bs[(wc * 64 + ni * 16 + lr) * 32 + lk];
#pragma unroll
    for (int mi = 0; mi < 4; ++mi)
#pragma unroll
      for (int ni = 0; ni < 4; ++ni)
        acc[mi][ni] = __builtin_amdgcn_mfma_f32_16x16x32_bf16(
            a[mi], b[ni], acc[mi][ni], 0, 0, 0);
    __syncthreads();
  }

  // C/D layout: col=lane&15, row=(lane>>4)*4+r  [measured m89/m91]
#pragma unroll
  for (int mi = 0; mi < 4; ++mi) {
#pragma unroll
    for (int ni = 0; ni < 4; ++ni) {
      const int col = col0 + wc * 64 + ni * 16 + lr;
      const int rowb = row0 + wr * 64 + mi * 16 + (lane >> 4) * 4;
      if (MODE == 1) {
#pragma unroll
        for (int r = 0; r < 4; ++r)
          ((float*)Cout)[(size_t)(rowb + r) * N + col] = acc[mi][ni][r] + bias[col];
      } else if (MODE == 0) {
#pragma unroll
        for (int r = 0; r < 4; ++r)
          ((unsigned short*)Cout)[(size_t)(rowb + r) * N + col] = f2bf(acc[mi][ni][r]);
      } else {
        // Vt[(b*16+h)][d][t]: b=rowb>>11, t=rowb&2047, h=col>>6, d=col&63.
        // 4 consecutive t per lane -> packed 8B store (t0 % 4 == 0).
        const int bidx = rowb >> 11, t0 = rowb & 2047;
        const int hh = col >> 6, dd = col & 63;
        uint2 pk;
        pk.x = (unsigned)f2bf(acc[mi][ni][0]) | ((unsigned)f2bf(acc[mi][ni][1]) << 16);
        pk.y = (unsigned)f2bf(acc[mi][ni][2]) | ((unsigned)f2bf(acc[mi][ni][3]) << 16);
        size_t addr = (((size_t)(bidx * Hh + hh)) * Dd + dd) * (size_t)Tt + t0;
        *(uint2*)((unsigned short*)Cout + addr) = pk;
      }
    }
  }
}

// ---------------- flash attention ------------------------------------------
// Q,K,O in [B,T,C] layout (head h at cols h*64..); V pre-transposed to
// Vt[b*16+h][d=64][t=2048]. Block: 4 waves, each owns 16 q rows. KV tile 64.
// K and Vt LDS tiles: rows of 128B, 16B chunks XOR-swizzled (chunk ^= row&7)
// via pre-swizzled global_load_lds SOURCE addresses (linear LDS dest, G21).
// PV computed as O^T = Vt @ P^T so both MFMA operands are contiguous reads.
__global__ __launch_bounds__(256, 2)
void flash_attn(const unsigned short* __restrict__ Q,
                const unsigned short* __restrict__ Km,
                const unsigned short* __restrict__ Vt,
                unsigned short* __restrict__ O) {
  __shared__ unsigned short Ks[KVB * 64];     // [kv][d], swizzled
  __shared__ unsigned short Vts[64 * KVB];    // [d][kv], swizzled
  __shared__ unsigned short Ps[4][16 * 72];   // [q][kv], +8 pad -> 144B rows
  __shared__ float Bcast[4][16];              // per-wave alpha / l broadcast

  const int tid = threadIdx.x;
  const int lane = tid & 63;
  const int w = tid >> 6;
  const int bh = blockIdx.x;                  // 0..63
  const int qt = blockIdx.y;                  // 0..31
  const int b = bh >> 4, h = bh & 15;
  const size_t base = (size_t)b * Tt * Cc + (size_t)h * Dd;
  const size_t vtbase = (size_t)bh * Dd * Tt;
  const int lr = lane & 15, lg = lane >> 4, lk = lg * 8;
  const int qrow0 = qt * 64 + w * 16;
  const int sw = lr & 7;                      // read-side swizzle key

  // Q fragments (A-operand), pre-scaled by 1/sqrt(D)=0.125 (exact)
  bf8 qa[2];
#pragma unroll
  for (int kk = 0; kk < 2; ++kk) {
    bf8 t = *(const bf8*)(Q + base + (size_t)(qrow0 + lr) * Cc + kk * 32 + lk);
#pragma unroll
    for (int i = 0; i < 8; ++i)
      qa[kk][i] = (short)f2bf(bf2f((unsigned short)t[i]) * 0.125f);
  }

  float m_r[4], l_r[4];
  f32x4 o_acc[4] = {};   // O^T: lane holds q=lr, d = dt*16 + lg*4 + r
#pragma unroll
  for (int r = 0; r < 4; ++r) { m_r[r] = -INFINITY; l_r[r] = 0.f; }

  // staging: thread t -> dest row (t>>3), chunk (t&7); source chunk ^= row&7
  const int strow = tid >> 3;                 // 0..31
  const int stch = tid & 7;
  const unsigned short* ksrc = Km + base + (size_t)strow * Cc + (stch ^ (strow & 7)) * 8;
  const unsigned short* vsrc = Vt + vtbase + (size_t)strow * Tt + (stch ^ (strow & 7)) * 8;
  unsigned short* kdst = &Ks[tid * 8];        // tid*16 bytes
  unsigned short* vdst = &Vts[tid * 8];

  for (int kb = 0; kb < Tt; kb += KVB) {
    // stage K rows kb..kb+63 (swizzle key (row+32)&7 == row&7)
    gl_lds16(ksrc + (size_t)kb * Cc,               kdst);
    gl_lds16(ksrc + (size_t)(kb + 32) * Cc,        kdst + 2048);
    gl_lds16(vsrc + kb,                            vdst);
    gl_lds16(vsrc + kb + (size_t)32 * Tt,          vdst + 2048);
    __syncthreads();

    // QK^T: S[16q][64kv] per wave, 4 n-tiles x K=64 chain
    f32x4 s[4];
#pragma unroll
    for (int nt = 0; nt < 4; ++nt) {
      const int row = nt * 16 + lr;
      bf8 k0 = *(const bf8*)&Ks[row * 64 + ((lg ^ sw) * 8)];
      bf8 k1 = *(const bf8*)&Ks[row * 64 + (((4 + lg) ^ sw) * 8)];
      f32x4 z = {};
      z = __builtin_amdgcn_mfma_f32_16x16x32_bf16(qa[0], k0, z, 0, 0, 0);
      z = __builtin_amdgcn_mfma_f32_16x16x32_bf16(qa[1], k1, z, 0, 0, 0);
      s[nt] = z;
    }

    // online softmax; lane holds S[q=lg*4+r][kv=nt*16+lr]
    float mt[4];
#pragma unroll
    for (int r = 0; r < 4; ++r)
      mt[r] = fmaxf(fmaxf(s[0][r], s[1][r]), fmaxf(s[2][r], s[3][r]));
#pragma unroll
    for (int mask = 1; mask < 16; mask <<= 1)
#pragma unroll
      for (int r = 0; r < 4; ++r) mt[r] = fmaxf(mt[r], __shfl_xor(mt[r], mask));

    float alpha[4];
#pragma unroll
    for (int r = 0; r < 4; ++r) {
      float mn = fmaxf(m_r[r], mt[r]);
      alpha[r] = __expf(m_r[r] - mn);
      m_r[r] = mn;
    }

    float psum[4] = {0.f, 0.f, 0.f, 0.f};
#pragma unroll
    for (int nt = 0; nt < 4; ++nt)
#pragma unroll
      for (int r = 0; r < 4; ++r) {
        float p = __expf(s[nt][r] - m_r[r]);
        psum[r] += p;
        Ps[w][(lg * 4 + r) * 72 + nt * 16 + lr] = f2bf(p);
      }
#pragma unroll
    for (int mask = 1; mask < 16; mask <<= 1)
#pragma unroll
      for (int r = 0; r < 4; ++r) psum[r] += __shfl_xor(psum[r], mask);
#pragma unroll
    for (int r = 0; r < 4; ++r) l_r[r] = l_r[r] * alpha[r] + psum[r];
    if (lr == 0) {
#pragma unroll
      for (int r = 0; r < 4; ++r) Bcast[w][lg * 4 + r] = alpha[r];
    }
    asm volatile("s_waitcnt lgkmcnt(0)" ::: "memory");
    __builtin_amdgcn_sched_barrier(0);

    // rescale O^T by alpha[q=lr] (per-lane scalar)
    const float al = Bcast[w][lr];
#pragma unroll
    for (int dt = 0; dt < 4; ++dt)
#pragma unroll
      for (int r = 0; r < 4; ++r) o_acc[dt][r] *= al;

    // PV: O^T[64d][16q] += Vt[64d][64kv] @ P^T[64kv][16q]
    bf8 pb0 = *(const bf8*)&Ps[w][lr * 72 + lk];        // k 0..31
    bf8 pb1 = *(const bf8*)&Ps[w][lr * 72 + 32 + lk];   // k 32..63
#pragma unroll
    for (int dt = 0; dt < 4; ++dt) {
      const int rowd = dt * 16 + lr;
      bf8 v0 = *(const bf8*)&Vts[rowd * 64 + ((lg ^ sw) * 8)];
      bf8 v1 = *(const bf8*)&Vts[rowd * 64 + (((4 + lg) ^ sw) * 8)];
      o_acc[dt] = __builtin_amdgcn_mfma_f32_16x16x32_bf16(v0, pb0, o_acc[dt], 0, 0, 0);
      o_acc[dt] = __builtin_amdgcn_mfma_f32_16x16x32_bf16(v1, pb1, o_acc[dt], 0, 0, 0);
    }
    __syncthreads();
  }

  // epilogue: broadcast l, normalize, packed 8B stores
  if (lr == 0) {
#pragma unroll
    for (int r = 0; r < 4; ++r) Bcast[w][lg * 4 + r] = l_r[r];
  }
  asm volatile("s_waitcnt lgkmcnt(0)" ::: "memory");
  __builtin_amdgcn_sched_barrier(0);
  const float linv = 1.0f / Bcast[w][lr];
#pragma unroll
  for (int dt = 0; dt < 4; ++dt) {
    uint2 pk;
    pk.x = (unsigned)f2bf(o_acc[dt][0] * linv) | ((unsigned)f2bf(o_acc[dt][1] * linv) << 16);
    pk.y = (unsigned)f2bf(o_acc[dt][2] * linv) | ((unsigned)f2bf(o_acc[dt][3] * linv) << 16);
    *(uint2*)(O + base + (size_t)(qrow0 + lr) * Cc + dt * 16 + lg * 4) = pk;
  }
}

// ---------------- host launcher --------------------------------------------
extern "C" void kernel_launch(void* const* d_in, const int* in_sizes, int n_in,
                              void* d_out, int out_size, void* d_ws, size_t ws_size,
                              hipStream_t stream) {
  (void)in_sizes; (void)n_in; (void)out_size; (void)ws_size;
  const float* hs = (const float*)d_in[0];
  const float* wq = (const float*)d_in[1];
  const float* wk = (const float*)d_in[2];
  const float* wv = (const float*)d_in[3];
  const float* wo = (const float*)d_in[4];
  const float* bo = (const float*)d_in[5];

  // workspace layout (bf16), 72 MB. Xb dead after QKV proj -> attn out reuses it.
  char* ws = (char*)d_ws;
  const size_t MB = 1u << 20;
  unsigned short* Xb  = (unsigned short*)(ws + 0);        // 16 MB (later: attn out)
  unsigned short* Wqb = (unsigned short*)(ws + 16 * MB);
  unsigned short* Wkb = (unsigned short*)(ws + 18 * MB);
  unsigned short* Wvb = (unsigned short*)(ws + 20 * MB);
  unsigned short* Wob = (unsigned short*)(ws + 22 * MB);
  unsigned short* Qb  = (unsigned short*)(ws + 24 * MB);
  unsigned short* Kb  = (unsigned short*)(ws + 40 * MB);
  unsigned short* Vtb = (unsigned short*)(ws + 56 * MB);  // transposed V
  unsigned short* Ob  = Xb;

  cast_f32_bf16<<<(Mm * Cc) / (256 * 8), 256, 0, stream>>>(hs, Xb, Mm * Cc);
  cast_f32_bf16<<<(Cc * Cc) / (256 * 8), 256, 0, stream>>>(wq, Wqb, Cc * Cc);
  cast_f32_bf16<<<(Cc * Cc) / (256 * 8), 256, 0, stream>>>(wk, Wkb, Cc * Cc);
  cast_f32_bf16<<<(Cc * Cc) / (256 * 8), 256, 0, stream>>>(wv, Wvb, Cc * Cc);
  cast_f32_bf16<<<(Cc * Cc) / (256 * 8), 256, 0, stream>>>(wo, Wob, Cc * Cc);

  dim3 gg(Cc / 128, Mm / 128);  // (8, 64)
  gemm_bt<0><<<gg, 256, 0, stream>>>(Xb, Wqb, Qb, nullptr, Mm, Cc, Cc);
  gemm_bt<0><<<gg, 256, 0, stream>>>(Xb, Wkb, Kb, nullptr, Mm, Cc, Cc);
  gemm_bt<2><<<gg, 256, 0, stream>>>(Xb, Wvb, Vtb, nullptr, Mm, Cc, Cc);

  flash_attn<<<dim3(Bb * Hh, Tt / 64), 256, 0, stream>>>(Qb, Kb, Vtb, Ob);

  gemm_bt<1><<<gg, 256, 0, stream>>>(Ob, Wob, (float*)d_out, bo, Mm, Cc, Cc);
}

// Round 5
// 338.488 us; speedup vs baseline: 1.5882x; 1.0002x over previous
//
#include <hip/hip_runtime.h>
#include <hip/hip_bf16.h>
#include <stdint.h>
#include <math.h>

// Problem constants
#define Bb 4
#define Tt 2048
#define Cc 1024
#define Hh 16
#define Dd 64
#define Mm (Bb * Tt)   // 8192 rows
#define KVB 64
#define NT (Tt / KVB)  // 32 kv tiles

typedef __attribute__((ext_vector_type(8))) short bf8;     // 8 x bf16 (4 VGPRs), MFMA A/B frag
typedef __attribute__((ext_vector_type(4))) float f32x4;   // MFMA C/D frag
typedef __attribute__((ext_vector_type(8))) unsigned short u16x8;

// log2(e)/8: folds both the 1/sqrt(D) scale and the exp->exp2 conversion into Q
#define QSCALE 0.1803368801111244f

__device__ __forceinline__ unsigned short f2bf(float f) {
  __hip_bfloat16 h = __float2bfloat16(f);   // native v_cvt, RNE
  return *reinterpret_cast<unsigned short*>(&h);
}
__device__ __forceinline__ float bf2f(unsigned short s) {
  union { unsigned u; float f; } v; v.u = ((unsigned)s) << 16;
  return v.f;
}
__device__ __forceinline__ float fexp2(float x) {
#if __has_builtin(__builtin_amdgcn_exp2f)
  return __builtin_amdgcn_exp2f(x);
#else
  return exp2f(x);
#endif
}
__device__ __forceinline__ void gl_lds16(const void* g, void* l) {
  __builtin_amdgcn_global_load_lds(
      (const __attribute__((address_space(1))) void*)g,
      (__attribute__((address_space(3))) void*)l, 16, 0, 0);
}

// ---------------- fp32 -> bf16 cast, 8 elems/thread -------------------------
__global__ __launch_bounds__(256) void cast_f32_bf16(
    const float* __restrict__ in, unsigned short* __restrict__ out, int n) {
  int i = (blockIdx.x * 256 + threadIdx.x) * 8;
  if (i >= n) return;
  const float4* p = (const float4*)(in + i);
  float4 a = p[0], b = p[1];
  u16x8 o;
  o[0] = f2bf(a.x); o[1] = f2bf(a.y); o[2] = f2bf(a.z); o[3] = f2bf(a.w);
  o[4] = f2bf(b.x); o[5] = f2bf(b.y); o[6] = f2bf(b.z); o[7] = f2bf(b.w);
  *(u16x8*)(out + i) = o;
}

// ---------------- bt-GEMM: C[M,N] = A[M,K] @ Bw[N,K]^T ----------------------
// MODE 0: bf16 row-major out. MODE 1: f32 out + bias. MODE 2: bf16 out in
// transposed attention layout Vt[b*16+h][d][t] (for the V projection).
template <int MODE>
__global__ __launch_bounds__(256, 2)
void gemm_bt(const unsigned short* __restrict__ A,
             const unsigned short* __restrict__ Bw,
             void* __restrict__ Cout,
             const float* __restrict__ bias,
             int M, int N, int K) {
  __shared__ unsigned short As[128 * 32];
  __shared__ unsigned short Bs[128 * 32];
  const int tid = threadIdx.x;
  const int lane = tid & 63;
  const int w = tid >> 6;
  const int wr = w >> 1, wc = w & 1;                 // 2x2 wave grid
  const int row0 = blockIdx.y * 128;
  const int col0 = blockIdx.x * 128;
  const int lr = lane & 15;                          // frag row within 16
  const int lk = (lane >> 4) * 8;                    // frag k offset

  f32x4 acc[4][4] = {};

  const int sr = tid >> 2;          // 0..63 (row within 64-row chunk)
  const int sc = (tid & 3) * 8;     // k-elem offset (16B granules)

  for (int k0 = 0; k0 < K; k0 += 32) {
    gl_lds16(A  + (size_t)(row0 + sr) * K + k0 + sc,      &As[sr * 32 + sc]);
    gl_lds16(A  + (size_t)(row0 + 64 + sr) * K + k0 + sc, &As[(64 + sr) * 32 + sc]);
    gl_lds16(Bw + (size_t)(col0 + sr) * K + k0 + sc,      &Bs[sr * 32 + sc]);
    gl_lds16(Bw + (size_t)(col0 + 64 + sr) * K + k0 + sc, &Bs[(64 + sr) * 32 + sc]);
    __syncthreads();

    bf8 a[4], b[4];
#pragma unroll
    for (int mi = 0; mi < 4; ++mi)
      a[mi] = *(const bf8*)&As[(wr * 64 + mi * 16 + lr) * 32 + lk];
#pragma unroll
    for (int ni = 0; ni < 4; ++ni)
      b[ni] = *(const bf8*)&Bs[(wc * 64 + ni * 16 + lr) * 32 + lk];
#pragma unroll
    for (int mi = 0; mi < 4; ++mi)
#pragma unroll
      for (int ni = 0; ni < 4; ++ni)
        acc[mi][ni] = __builtin_amdgcn_mfma_f32_16x16x32_bf16(
            a[mi], b[ni], acc[mi][ni], 0, 0, 0);
    __syncthreads();
  }

  // C/D layout: col=lane&15, row=(lane>>4)*4+r  [measured m89/m91]
#pragma unroll
  for (int mi = 0; mi < 4; ++mi) {
#pragma unroll
    for (int ni = 0; ni < 4; ++ni) {
      const int col = col0 + wc * 64 + ni * 16 + lr;
      const int rowb = row0 + wr * 64 + mi * 16 + (lane >> 4) * 4;
      if (MODE == 1) {
#pragma unroll
        for (int r = 0; r < 4; ++r)
          ((float*)Cout)[(size_t)(rowb + r) * N + col] = acc[mi][ni][r] + bias[col];
      } else if (MODE == 0) {
#pragma unroll
        for (int r = 0; r < 4; ++r)
          ((unsigned short*)Cout)[(size_t)(rowb + r) * N + col] = f2bf(acc[mi][ni][r]);
      } else {
        // Vt[(b*16+h)][d][t]: b=rowb>>11, t=rowb&2047, h=col>>6, d=col&63.
        const int bidx = rowb >> 11, t0 = rowb & 2047;
        const int hh = col >> 6, dd = col & 63;
        uint2 pk;
        pk.x = (unsigned)f2bf(acc[mi][ni][0]) | ((unsigned)f2bf(acc[mi][ni][1]) << 16);
        pk.y = (unsigned)f2bf(acc[mi][ni][2]) | ((unsigned)f2bf(acc[mi][ni][3]) << 16);
        size_t addr = (((size_t)(bidx * Hh + hh)) * Dd + dd) * (size_t)Tt + t0;
        *(uint2*)((unsigned short*)Cout + addr) = pk;
      }
    }
  }
}

// ---------------- flash attention ------------------------------------------
// Q,K,O in [B,T,C] layout (head h at cols h*64..); V pre-transposed to
// Vt[b*16+h][d=64][t=2048]. Block: 4 waves, each owns 16 q rows. KV tile 64,
// double-buffered (2-phase pipeline, one barrier per tile).
// K/Vt LDS tiles XOR-swizzled via pre-swizzled global SOURCE addrs (G21).
// Softmax in exp2 domain (log2e/8 folded into Q prescale), defer-max THR=8.
// PV computed as O^T = Vt @ P^T so both MFMA operands are contiguous reads.
__global__ __launch_bounds__(256, 2)
void flash_attn(const unsigned short* __restrict__ Q,
                const unsigned short* __restrict__ Km,
                const unsigned short* __restrict__ Vt,
                unsigned short* __restrict__ O) {
  __shared__ unsigned short Ks[2][KVB * 64];     // [kv][d], swizzled
  __shared__ unsigned short Vts[2][64 * KVB];    // [d][kv], swizzled
  __shared__ unsigned short Ps[4][16 * 72];      // [q][kv], +8 pad
  __shared__ float Bcast[4][16];                 // per-wave alpha / l broadcast

  const int tid = threadIdx.x;
  const int lane = tid & 63;
  const int w = tid >> 6;
  const int bh = blockIdx.x;                  // 0..63
  const int qt = blockIdx.y;                  // 0..31
  const int b = bh >> 4, h = bh & 15;
  const size_t base = (size_t)b * Tt * Cc + (size_t)h * Dd;
  const size_t vtbase = (size_t)bh * Dd * Tt;
  const int lr = lane & 15, lg = lane >> 4, lk = lg * 8;
  const int qrow0 = qt * 64 + w * 16;
  const int sw = lr & 7;                      // read-side swizzle key

  // Q fragments (A-operand), pre-scaled by log2(e)/sqrt(D)
  bf8 qa[2];
#pragma unroll
  for (int kk = 0; kk < 2; ++kk) {
    bf8 t = *(const bf8*)(Q + base + (size_t)(qrow0 + lr) * Cc + kk * 32 + lk);
#pragma unroll
    for (int i = 0; i < 8; ++i)
      qa[kk][i] = (short)f2bf(bf2f((unsigned short)t[i]) * QSCALE);
  }

  float m_r[4], l_r[4];
  f32x4 o_acc[4] = {};   // O^T: lane holds q=lr, d = dt*16 + lg*4 + r
#pragma unroll
  for (int r = 0; r < 4; ++r) { m_r[r] = -INFINITY; l_r[r] = 0.f; }

  // staging: thread t -> dest chunk tid (linear); source chunk ^= row&7
  const int strow = tid >> 3;                 // 0..31
  const int stch = tid & 7;
  const unsigned short* ksrc = Km + base + (size_t)strow * Cc + (stch ^ (strow & 7)) * 8;
  const unsigned short* vsrc = Vt + vtbase + (size_t)strow * Tt + (stch ^ (strow & 7)) * 8;

  // prologue: stage tile 0 into buffer 0
  {
    gl_lds16(ksrc,                     &Ks[0][tid * 8]);
    gl_lds16(ksrc + (size_t)32 * Cc,   &Ks[0][tid * 8 + 2048]);
    gl_lds16(vsrc,                     &Vts[0][tid * 8]);
    gl_lds16(vsrc + (size_t)32 * Tt,   &Vts[0][tid * 8 + 2048]);
  }
  __syncthreads();

  for (int t = 0; t < NT; ++t) {
    const int cur = t & 1;
    if (t + 1 < NT) {  // prefetch next tile into other buffer
      const int kb = (t + 1) * KVB;
      gl_lds16(ksrc + (size_t)kb * Cc,        &Ks[cur ^ 1][tid * 8]);
      gl_lds16(ksrc + (size_t)(kb + 32) * Cc, &Ks[cur ^ 1][tid * 8 + 2048]);
      gl_lds16(vsrc + kb,                     &Vts[cur ^ 1][tid * 8]);
      gl_lds16(vsrc + kb + (size_t)32 * Tt,   &Vts[cur ^ 1][tid * 8 + 2048]);
    }

    // QK^T: S[16q][64kv] per wave, 4 n-tiles x K=64 chain
    f32x4 s[4];
#pragma unroll
    for (int nt = 0; nt < 4; ++nt) {
      const int row = nt * 16 + lr;
      bf8 k0 = *(const bf8*)&Ks[cur][row * 64 + ((lg ^ sw) * 8)];
      bf8 k1 = *(const bf8*)&Ks[cur][row * 64 + (((4 + lg) ^ sw) * 8)];
      f32x4 z = {};
      z = __builtin_amdgcn_mfma_f32_16x16x32_bf16(qa[0], k0, z, 0, 0, 0);
      z = __builtin_amdgcn_mfma_f32_16x16x32_bf16(qa[1], k1, z, 0, 0, 0);
      s[nt] = z;
    }

    // online softmax (log2 domain); lane holds S[q=lg*4+r][kv=nt*16+lr]
    float mt[4];
#pragma unroll
    for (int r = 0; r < 4; ++r)
      mt[r] = fmaxf(fmaxf(s[0][r], s[1][r]), fmaxf(s[2][r], s[3][r]));
#pragma unroll
    for (int mask = 1; mask < 16; mask <<= 1)
#pragma unroll
      for (int r = 0; r < 4; ++r) mt[r] = fmaxf(mt[r], __shfl_xor(mt[r], mask));

    // defer-max (T13): rescale only when some row grew by > 8 (in log2 units)
    bool need = false;
#pragma unroll
    for (int r = 0; r < 4; ++r) need |= (mt[r] > m_r[r] + 8.0f);
    if (__any(need)) {
      float alpha[4];
#pragma unroll
      for (int r = 0; r < 4; ++r) {
        float mn = fmaxf(m_r[r], mt[r]);
        alpha[r] = fexp2(m_r[r] - mn);   // 0 on first tile
        m_r[r] = mn;
        l_r[r] *= alpha[r];
      }
      if (lr == 0) {
#pragma unroll
        for (int r = 0; r < 4; ++r) Bcast[w][lg * 4 + r] = alpha[r];
      }
      const float al = Bcast[w][lr];   // per-wave buffer; wave DS ops in order
#pragma unroll
      for (int dt = 0; dt < 4; ++dt)
#pragma unroll
        for (int r = 0; r < 4; ++r) o_acc[dt][r] *= al;
    }

    float psum[4] = {0.f, 0.f, 0.f, 0.f};
#pragma unroll
    for (int nt = 0; nt < 4; ++nt)
#pragma unroll
      for (int r = 0; r < 4; ++r) {
        float p = fexp2(s[nt][r] - m_r[r]);
        psum[r] += p;
        Ps[w][(lg * 4 + r) * 72 + nt * 16 + lr] = f2bf(p);
      }
#pragma unroll
    for (int mask = 1; mask < 16; mask <<= 1)
#pragma unroll
      for (int r = 0; r < 4; ++r) psum[r] += __shfl_xor(psum[r], mask);
#pragma unroll
    for (int r = 0; r < 4; ++r) l_r[r] += psum[r];

    // PV: O^T[64d][16q] += Vt[64d][64kv] @ P^T[64kv][16q]
    bf8 pb0 = *(const bf8*)&Ps[w][lr * 72 + lk];        // k 0..31
    bf8 pb1 = *(const bf8*)&Ps[w][lr * 72 + 32 + lk];   // k 32..63
#pragma unroll
    for (int dt = 0; dt < 4; ++dt) {
      const int rowd = dt * 16 + lr;
      bf8 v0 = *(const bf8*)&Vts[cur][rowd * 64 + ((lg ^ sw) * 8)];
      bf8 v1 = *(const bf8*)&Vts[cur][rowd * 64 + (((4 + lg) ^ sw) * 8)];
      o_acc[dt] = __builtin_amdgcn_mfma_f32_16x16x32_bf16(v0, pb0, o_acc[dt], 0, 0, 0);
      o_acc[dt] = __builtin_amdgcn_mfma_f32_16x16x32_bf16(v1, pb1, o_acc[dt], 0, 0, 0);
    }
    __syncthreads();   // drains prefetch vmcnt + all waves done reading cur
  }

  // epilogue: broadcast l, normalize, packed 8B stores
  if (lr == 0) {
#pragma unroll
    for (int r = 0; r < 4; ++r) Bcast[w][lg * 4 + r] = l_r[r];
  }
  const float linv = 1.0f / Bcast[w][lr];
#pragma unroll
  for (int dt = 0; dt < 4; ++dt) {
    uint2 pk;
    pk.x = (unsigned)f2bf(o_acc[dt][0] * linv) | ((unsigned)f2bf(o_acc[dt][1] * linv) << 16);
    pk.y = (unsigned)f2bf(o_acc[dt][2] * linv) | ((unsigned)f2bf(o_acc[dt][3] * linv) << 16);
    *(uint2*)(O + base + (size_t)(qrow0 + lr) * Cc + dt * 16 + lg * 4) = pk;
  }
}

// ---------------- host launcher --------------------------------------------
extern "C" void kernel_launch(void* const* d_in, const int* in_sizes, int n_in,
                              void* d_out, int out_size, void* d_ws, size_t ws_size,
                              hipStream_t stream) {
  (void)in_sizes; (void)n_in; (void)out_size; (void)ws_size;
  const float* hs = (const float*)d_in[0];
  const float* wq = (const float*)d_in[1];
  const float* wk = (const float*)d_in[2];
  const float* wv = (const float*)d_in[3];
  const float* wo = (const float*)d_in[4];
  const float* bo = (const float*)d_in[5];

  // workspace layout (bf16), 72 MB. Xb dead after QKV proj -> attn out reuses it.
  char* ws = (char*)d_ws;
  const size_t MB = 1u << 20;
  unsigned short* Xb  = (unsigned short*)(ws + 0);        // 16 MB (later: attn out)
  unsigned short* Wqb = (unsigned short*)(ws + 16 * MB);
  unsigned short* Wkb = (unsigned short*)(ws + 18 * MB);
  unsigned short* Wvb = (unsigned short*)(ws + 20 * MB);
  unsigned short* Wob = (unsigned short*)(ws + 22 * MB);
  unsigned short* Qb  = (unsigned short*)(ws + 24 * MB);
  unsigned short* Kb  = (unsigned short*)(ws + 40 * MB);
  unsigned short* Vtb = (unsigned short*)(ws + 56 * MB);  // transposed V
  unsigned short* Ob  = Xb;

  cast_f32_bf16<<<(Mm * Cc) / (256 * 8), 256, 0, stream>>>(hs, Xb, Mm * Cc);
  cast_f32_bf16<<<(Cc * Cc) / (256 * 8), 256, 0, stream>>>(wq, Wqb, Cc * Cc);
  cast_f32_bf16<<<(Cc * Cc) / (256 * 8), 256, 0, stream>>>(wk, Wkb, Cc * Cc);
  cast_f32_bf16<<<(Cc * Cc) / (256 * 8), 256, 0, stream>>>(wv, Wvb, Cc * Cc);
  cast_f32_bf16<<<(Cc * Cc) / (256 * 8), 256, 0, stream>>>(wo, Wob, Cc * Cc);

  dim3 gg(Cc / 128, Mm / 128);  // (8, 64)
  gemm_bt<0><<<gg, 256, 0, stream>>>(Xb, Wqb, Qb, nullptr, Mm, Cc, Cc);
  gemm_bt<0><<<gg, 256, 0, stream>>>(Xb, Wkb, Kb, nullptr, Mm, Cc, Cc);
  gemm_bt<2><<<gg, 256, 0, stream>>>(Xb, Wvb, Vtb, nullptr, Mm, Cc, Cc);

  flash_attn<<<dim3(Bb * Hh, Tt / 64), 256, 0, stream>>>(Qb, Kb, Vtb, Ob);

  gemm_bt<1><<<gg, 256, 0, stream>>>(Ob, Wob, (float*)d_out, bo, Mm, Cc, Cc);
}

// Round 7
// 244.303 us; speedup vs baseline: 2.2005x; 1.3855x over previous
//
#include <hip/hip_runtime.h>
#include <hip/hip_bf16.h>
#include <stdint.h>
#include <math.h>

// Problem constants
#define Bb 4
#define Tt 2048
#define Cc 1024
#define Hh 16
#define Dd 64
#define Mm (Bb * Tt)   // 8192 rows
#define KVB 64
#define NT (Tt / KVB)  // 32 kv tiles

typedef __attribute__((ext_vector_type(8))) short bf8;     // 8 x bf16 (4 VGPRs), MFMA A/B frag
typedef __attribute__((ext_vector_type(4))) float f32x4;   // MFMA C/D frag
typedef __attribute__((ext_vector_type(8))) unsigned short u16x8;

// log2(e)/8: folds both the 1/sqrt(D) scale and the exp->exp2 conversion into Q
#define QSCALE 0.1803368801111244f

__device__ __forceinline__ unsigned short f2bf(float f) {
  __hip_bfloat16 h = __float2bfloat16(f);   // native v_cvt, RNE
  return *reinterpret_cast<unsigned short*>(&h);
}
__device__ __forceinline__ float bf2f(unsigned short s) {
  union { unsigned u; float f; } v; v.u = ((unsigned)s) << 16;
  return v.f;
}
__device__ __forceinline__ float fexp2(float x) {
#if __has_builtin(__builtin_amdgcn_exp2f)
  return __builtin_amdgcn_exp2f(x);
#else
  return exp2f(x);
#endif
}
__device__ __forceinline__ void gl_lds16(const void* g, void* l) {
  __builtin_amdgcn_global_load_lds(
      (const __attribute__((address_space(1))) void*)g,
      (__attribute__((address_space(3))) void*)l, 16, 0, 0);
}

// ---------------- fp32 -> bf16 cast, 8 elems/thread -------------------------
__global__ __launch_bounds__(256) void cast_f32_bf16(
    const float* __restrict__ in, unsigned short* __restrict__ out, int n) {
  int i = (blockIdx.x * 256 + threadIdx.x) * 8;
  if (i >= n) return;
  const float4* p = (const float4*)(in + i);
  float4 a = p[0], b = p[1];
  u16x8 o;
  o[0] = f2bf(a.x); o[1] = f2bf(a.y); o[2] = f2bf(a.z); o[3] = f2bf(a.w);
  o[4] = f2bf(b.x); o[5] = f2bf(b.y); o[6] = f2bf(b.z); o[7] = f2bf(b.w);
  *(u16x8*)(out + i) = o;
}

// ---------------- bt-GEMM: C[M,N] = A[M,K] @ Bw[N,K]^T ----------------------
// MODE 0: bf16 row-major out. MODE 1: f32 out + bias. MODE 2: bf16 out in
// transposed attention layout Vt[b*16+h][d][t] (for the V projection).
template <int MODE>
__global__ __launch_bounds__(256, 2)
void gemm_bt(const unsigned short* __restrict__ A,
             const unsigned short* __restrict__ Bw,
             void* __restrict__ Cout,
             const float* __restrict__ bias,
             int M, int N, int K) {
  __shared__ unsigned short As[128 * 32];
  __shared__ unsigned short Bs[128 * 32];
  const int tid = threadIdx.x;
  const int lane = tid & 63;
  const int w = tid >> 6;
  const int wr = w >> 1, wc = w & 1;                 // 2x2 wave grid
  const int row0 = blockIdx.y * 128;
  const int col0 = blockIdx.x * 128;
  const int lr = lane & 15;                          // frag row within 16
  const int lk = (lane >> 4) * 8;                    // frag k offset

  f32x4 acc[4][4] = {};

  const int sr = tid >> 2;          // 0..63 (row within 64-row chunk)
  const int sc = (tid & 3) * 8;     // k-elem offset (16B granules)

  for (int k0 = 0; k0 < K; k0 += 32) {
    gl_lds16(A  + (size_t)(row0 + sr) * K + k0 + sc,      &As[sr * 32 + sc]);
    gl_lds16(A  + (size_t)(row0 + 64 + sr) * K + k0 + sc, &As[(64 + sr) * 32 + sc]);
    gl_lds16(Bw + (size_t)(col0 + sr) * K + k0 + sc,      &Bs[sr * 32 + sc]);
    gl_lds16(Bw + (size_t)(col0 + 64 + sr) * K + k0 + sc, &Bs[(64 + sr) * 32 + sc]);
    __syncthreads();

    bf8 a[4], b[4];
#pragma unroll
    for (int mi = 0; mi < 4; ++mi)
      a[mi] = *(const bf8*)&As[(wr * 64 + mi * 16 + lr) * 32 + lk];
#pragma unroll
    for (int ni = 0; ni < 4; ++ni)
      b[ni] = *(const bf8*)&Bs[(wc * 64 + ni * 16 + lr) * 32 + lk];
#pragma unroll
    for (int mi = 0; mi < 4; ++mi)
#pragma unroll
      for (int ni = 0; ni < 4; ++ni)
        acc[mi][ni] = __builtin_amdgcn_mfma_f32_16x16x32_bf16(
            a[mi], b[ni], acc[mi][ni], 0, 0, 0);
    __syncthreads();
  }

  // C/D layout: col=lane&15, row=(lane>>4)*4+r  [measured m89/m91]
#pragma unroll
  for (int mi = 0; mi < 4; ++mi) {
#pragma unroll
    for (int ni = 0; ni < 4; ++ni) {
      const int col = col0 + wc * 64 + ni * 16 + lr;
      const int rowb = row0 + wr * 64 + mi * 16 + (lane >> 4) * 4;
      if (MODE == 1) {
#pragma unroll
        for (int r = 0; r < 4; ++r)
          ((float*)Cout)[(size_t)(rowb + r) * N + col] = acc[mi][ni][r] + bias[col];
      } else if (MODE == 0) {
#pragma unroll
        for (int r = 0; r < 4; ++r)
          ((unsigned short*)Cout)[(size_t)(rowb + r) * N + col] = f2bf(acc[mi][ni][r]);
      } else {
        // Vt[(b*16+h)][d][t]: b=rowb>>11, t=rowb&2047, h=col>>6, d=col&63.
        const int bidx = rowb >> 11, t0 = rowb & 2047;
        const int hh = col >> 6, dd = col & 63;
        uint2 pk;
        pk.x = (unsigned)f2bf(acc[mi][ni][0]) | ((unsigned)f2bf(acc[mi][ni][1]) << 16);
        pk.y = (unsigned)f2bf(acc[mi][ni][2]) | ((unsigned)f2bf(acc[mi][ni][3]) << 16);
        size_t addr = (((size_t)(bidx * Hh + hh)) * Dd + dd) * (size_t)Tt + t0;
        *(uint2*)((unsigned short*)Cout + addr) = pk;
      }
    }
  }
}

// ---------------- flash attention (swapped-operand, 8 waves) ----------------
// Q,K,O in [B,T,C] layout; V pre-transposed to Vt[b*16+h][d=64][t=2048].
// Block: 8 waves x 16 q rows = 128 q rows. KV tile 64, double-buffered,
// one barrier per tile. K/Vt LDS XOR-swizzled via pre-swizzled global
// source addresses (G21); linear LDS dest.
// QK^T computed SWAPPED: S^T = mfma(K_frag, Q_frag) -> lane holds
// S^T[kv=nt*16+lg*4+r][q=lr]: all 16 kv of one q row per lane. Softmax
// max/sum = in-lane tree + 2 shuffles; m/l/alpha are per-lane scalars
// (no LDS broadcast). P packed to u32 pairs (8 ds_write_b32), read back
// as B-operand of O^T = mfma(Vt_frag, P_frag). exp2 domain + defer-max.
__global__ __launch_bounds__(512, 4)
void flash_attn(const unsigned short* __restrict__ Q,
                const unsigned short* __restrict__ Km,
                const unsigned short* __restrict__ Vt,
                unsigned short* __restrict__ O) {
  __shared__ unsigned short Ks[2][KVB * 64];     // [kv][d], swizzled
  __shared__ unsigned short Vts[2][64 * KVB];    // [d][kv], swizzled
  __shared__ unsigned int Ps[8][16 * 36];        // [q][kv/2 u32], stride 144B

  const int tid = threadIdx.x;
  const int lane = tid & 63;
  const int w = tid >> 6;                     // 0..7
  const int bh = blockIdx.x;                  // 0..63
  const int qt = blockIdx.y;                  // 0..15
  const int b = bh >> 4, h = bh & 15;
  const size_t base = (size_t)b * Tt * Cc + (size_t)h * Dd;
  const size_t vtbase = (size_t)bh * Dd * Tt;
  const int lr = lane & 15, lg = lane >> 4;
  const int qrow0 = qt * 128 + w * 16;
  const int sw = lr & 7;                      // read-side swizzle key

  // Q fragments (B-operand now), pre-scaled by log2(e)/sqrt(D)
  bf8 qa[2];
#pragma unroll
  for (int kk = 0; kk < 2; ++kk) {
    bf8 t = *(const bf8*)(Q + base + (size_t)(qrow0 + lr) * Cc + kk * 32 + lg * 8);
#pragma unroll
    for (int i = 0; i < 8; ++i)
      qa[kk][i] = (short)f2bf(bf2f((unsigned short)t[i]) * QSCALE);
  }

  float m_r = -INFINITY, l_r = 0.f;   // per-lane scalars for q = lr
  f32x4 o_acc[4] = {};                // O^T: lane holds q=lr, d=dt*16+lg*4+r

  // staging: thread -> dest row (tid>>3), chunk (tid&7); src chunk ^= row&7
  const int strow = tid >> 3;                 // 0..63
  const int stch = tid & 7;
  const unsigned short* ksrc = Km + base + (size_t)strow * Cc + (stch ^ (strow & 7)) * 8;
  const unsigned short* vsrc = Vt + vtbase + (size_t)strow * Tt + (stch ^ (strow & 7)) * 8;

  // prologue: stage tile 0 into buffer 0 (512 thr x 16B = full 8KB tile each)
  gl_lds16(ksrc, &Ks[0][tid * 8]);
  gl_lds16(vsrc, &Vts[0][tid * 8]);
  __syncthreads();

  for (int t = 0; t < NT; ++t) {
    const int cur = t & 1;
    if (t + 1 < NT) {  // prefetch next tile into other buffer
      const int kb = (t + 1) * KVB;
      gl_lds16(ksrc + (size_t)kb * Cc, &Ks[cur ^ 1][tid * 8]);
      gl_lds16(vsrc + kb,              &Vts[cur ^ 1][tid * 8]);
    }

    // S^T[64kv][16q] = K[64kv][64d] @ Q^T[64d][16q]  (swapped operands)
    f32x4 s[4];
#pragma unroll
    for (int nt = 0; nt < 4; ++nt) {
      const int row = nt * 16 + lr;
      bf8 k0 = *(const bf8*)&Ks[cur][row * 64 + ((lg ^ sw) * 8)];
      bf8 k1 = *(const bf8*)&Ks[cur][row * 64 + (((4 + lg) ^ sw) * 8)];
      f32x4 z = {};
      z = __builtin_amdgcn_mfma_f32_16x16x32_bf16(k0, qa[0], z, 0, 0, 0);
      z = __builtin_amdgcn_mfma_f32_16x16x32_bf16(k1, qa[1], z, 0, 0, 0);
      s[nt] = z;
    }
    // lane holds S^T[kv=nt*16+lg*4+r][q=lr]: 16 kv samples of row q=lr

    // row max: in-lane tree over 16, then combine the 4 lg groups
    float mt;
    {
      float a0 = fmaxf(fmaxf(s[0][0], s[0][1]), fmaxf(s[0][2], s[0][3]));
      float a1 = fmaxf(fmaxf(s[1][0], s[1][1]), fmaxf(s[1][2], s[1][3]));
      float a2 = fmaxf(fmaxf(s[2][0], s[2][1]), fmaxf(s[2][2], s[2][3]));
      float a3 = fmaxf(fmaxf(s[3][0], s[3][1]), fmaxf(s[3][2], s[3][3]));
      mt = fmaxf(fmaxf(a0, a1), fmaxf(a2, a3));
    }
    mt = fmaxf(mt, __shfl_xor(mt, 16));
    mt = fmaxf(mt, __shfl_xor(mt, 32));

    // defer-max (T13): rescale only when some row grew by > 8 (log2 units)
    if (__any(mt > m_r + 8.0f)) {
      float mn = fmaxf(m_r, mt);
      float alpha = fexp2(m_r - mn);   // 0 on first tile
      m_r = mn;
      l_r *= alpha;
#pragma unroll
      for (int dt = 0; dt < 4; ++dt)
#pragma unroll
        for (int r = 0; r < 4; ++r) o_acc[dt][r] *= alpha;
    }

    // P = exp2(S - m), pack pairs to u32, stash per-wave (8 ds_write_b32)
    float psum = 0.f;
#pragma unroll
    for (int nt = 0; nt < 4; ++nt) {
      float p0 = fexp2(s[nt][0] - m_r);
      float p1 = fexp2(s[nt][1] - m_r);
      float p2 = fexp2(s[nt][2] - m_r);
      float p3 = fexp2(s[nt][3] - m_r);
      psum += (p0 + p1) + (p2 + p3);
      Ps[w][lr * 36 + nt * 8 + lg * 2 + 0] =
          (unsigned)f2bf(p0) | ((unsigned)f2bf(p1) << 16);
      Ps[w][lr * 36 + nt * 8 + lg * 2 + 1] =
          (unsigned)f2bf(p2) | ((unsigned)f2bf(p3) << 16);
    }
    psum += __shfl_xor(psum, 16);
    psum += __shfl_xor(psum, 32);
    l_r += psum;

    // P fragment: lane needs P[q=lr][kv=lg*8..lg*8+7] (+32 for second half)
    bf8 pb0 = *(const bf8*)&Ps[w][lr * 36 + lg * 4];
    bf8 pb1 = *(const bf8*)&Ps[w][lr * 36 + 16 + lg * 4];

    // PV: O^T[64d][16q] += Vt[64d][64kv] @ P^T[64kv][16q]
#pragma unroll
    for (int dt = 0; dt < 4; ++dt) {
      const int rowd = dt * 16 + lr;
      bf8 v0 = *(const bf8*)&Vts[cur][rowd * 64 + ((lg ^ sw) * 8)];
      bf8 v1 = *(const bf8*)&Vts[cur][rowd * 64 + (((4 + lg) ^ sw) * 8)];
      o_acc[dt] = __builtin_amdgcn_mfma_f32_16x16x32_bf16(v0, pb0, o_acc[dt], 0, 0, 0);
      o_acc[dt] = __builtin_amdgcn_mfma_f32_16x16x32_bf16(v1, pb1, o_acc[dt], 0, 0, 0);
    }
    __syncthreads();   // all waves done with cur; prefetch drained
  }

  // epilogue: per-lane normalize (q=lr), packed 8B stores
  const float linv = 1.0f / l_r;
#pragma unroll
  for (int dt = 0; dt < 4; ++dt) {
    uint2 pk;
    pk.x = (unsigned)f2bf(o_acc[dt][0] * linv) | ((unsigned)f2bf(o_acc[dt][1] * linv) << 16);
    pk.y = (unsigned)f2bf(o_acc[dt][2] * linv) | ((unsigned)f2bf(o_acc[dt][3] * linv) << 16);
    *(uint2*)(O + base + (size_t)(qrow0 + lr) * Cc + dt * 16 + lg * 4) = pk;
  }
}

// ---------------- host launcher --------------------------------------------
extern "C" void kernel_launch(void* const* d_in, const int* in_sizes, int n_in,
                              void* d_out, int out_size, void* d_ws, size_t ws_size,
                              hipStream_t stream) {
  (void)in_sizes; (void)n_in; (void)out_size; (void)ws_size;
  const float* hs = (const float*)d_in[0];
  const float* wq = (const float*)d_in[1];
  const float* wk = (const float*)d_in[2];
  const float* wv = (const float*)d_in[3];
  const float* wo = (const float*)d_in[4];
  const float* bo = (const float*)d_in[5];

  // workspace layout (bf16), 72 MB. Xb dead after QKV proj -> attn out reuses it.
  char* ws = (char*)d_ws;
  const size_t MB = 1u << 20;
  unsigned short* Xb  = (unsigned short*)(ws + 0);        // 16 MB (later: attn out)
  unsigned short* Wqb = (unsigned short*)(ws + 16 * MB);
  unsigned short* Wkb = (unsigned short*)(ws + 18 * MB);
  unsigned short* Wvb = (unsigned short*)(ws + 20 * MB);
  unsigned short* Wob = (unsigned short*)(ws + 22 * MB);
  unsigned short* Qb  = (unsigned short*)(ws + 24 * MB);
  unsigned short* Kb  = (unsigned short*)(ws + 40 * MB);
  unsigned short* Vtb = (unsigned short*)(ws + 56 * MB);  // transposed V
  unsigned short* Ob  = Xb;

  cast_f32_bf16<<<(Mm * Cc) / (256 * 8), 256, 0, stream>>>(hs, Xb, Mm * Cc);
  cast_f32_bf16<<<(Cc * Cc) / (256 * 8), 256, 0, stream>>>(wq, Wqb, Cc * Cc);
  cast_f32_bf16<<<(Cc * Cc) / (256 * 8), 256, 0, stream>>>(wk, Wkb, Cc * Cc);
  cast_f32_bf16<<<(Cc * Cc) / (256 * 8), 256, 0, stream>>>(wv, Wvb, Cc * Cc);
  cast_f32_bf16<<<(Cc * Cc) / (256 * 8), 256, 0, stream>>>(wo, Wob, Cc * Cc);

  dim3 gg(Cc / 128, Mm / 128);  // (8, 64)
  gemm_bt<0><<<gg, 256, 0, stream>>>(Xb, Wqb, Qb, nullptr, Mm, Cc, Cc);
  gemm_bt<0><<<gg, 256, 0, stream>>>(Xb, Wkb, Kb, nullptr, Mm, Cc, Cc);
  gemm_bt<2><<<gg, 256, 0, stream>>>(Xb, Wvb, Vtb, nullptr, Mm, Cc, Cc);

  flash_attn<<<dim3(Bb * Hh, Tt / 128), 512, 0, stream>>>(Qb, Kb, Vtb, Ob);

  gemm_bt<1><<<gg, 256, 0, stream>>>(Ob, Wob, (float*)d_out, bo, Mm, Cc, Cc);
}

// Round 10
// 199.464 us; speedup vs baseline: 2.6951x; 1.2248x over previous
//
#include <hip/hip_runtime.h>
#include <hip/hip_bf16.h>
#include <stdint.h>
#include <math.h>

// Problem constants
#define Bb 4
#define Tt 2048
#define Cc 1024
#define Hh 16
#define Dd 64
#define Mm (Bb * Tt)   // 8192 rows
#define KVB 64
#define NT (Tt / KVB)  // 32 kv tiles

typedef __attribute__((ext_vector_type(8))) short bf8;     // 8 x bf16, MFMA A/B frag
typedef __attribute__((ext_vector_type(4))) float f32x4;   // 16x16 C/D frag
typedef __attribute__((ext_vector_type(16))) float f32x16; // 32x32 C/D frag
typedef __attribute__((ext_vector_type(8))) unsigned short u16x8;

// log2(e)/8: folds the 1/sqrt(D) scale and exp->exp2 conversion into Q
#define QSCALE 0.1803368801111244f

__device__ __forceinline__ unsigned short f2bf(float f) {
  __hip_bfloat16 h = __float2bfloat16(f);   // native v_cvt, RNE
  return *reinterpret_cast<unsigned short*>(&h);
}
__device__ __forceinline__ float bf2f(unsigned short s) {
  union { unsigned u; float f; } v; v.u = ((unsigned)s) << 16;
  return v.f;
}
__device__ __forceinline__ float fexp2(float x) {
#if __has_builtin(__builtin_amdgcn_exp2f)
  return __builtin_amdgcn_exp2f(x);
#else
  return exp2f(x);
#endif
}
__device__ __forceinline__ unsigned cvtpk(float lo, float hi) {
  unsigned r;
  asm volatile("v_cvt_pk_bf16_f32 %0, %1, %2" : "=v"(r) : "v"(lo), "v"(hi));
  return r;
}
__device__ __forceinline__ void gl_lds16(const void* g, void* l) {
  __builtin_amdgcn_global_load_lds(
      (const __attribute__((address_space(1))) void*)g,
      (__attribute__((address_space(3))) void*)l, 16, 0, 0);
}

// ------------- fused fp32 -> bf16 cast: hs + 4 weights, one launch ----------
// Segments: [0, 8M) hs -> Xb; [8M, 12M): weight w=(idx-8M)>>20 -> Wq base +
// w*1M (Wq/Wk/Wv/Wo are contiguous 1M-elem slots). Blocks never straddle
// segment boundaries (2048-elem blocks; boundaries are multiples of 1M).
__global__ __launch_bounds__(256) void cast_all(
    const float* __restrict__ hs, const float* __restrict__ wq,
    const float* __restrict__ wk, const float* __restrict__ wv,
    const float* __restrict__ wo, unsigned short* __restrict__ Xb,
    unsigned short* __restrict__ Wbase) {
  long long g = (long long)(blockIdx.x * 256 + threadIdx.x) * 8;
  const float* src;
  unsigned short* dst;
  long long off;
  const long long HS = 8LL * 1024 * 1024;
  if (g < HS) {
    src = hs; dst = Xb; off = g;
  } else {
    long long r = g - HS;
    int wsel = (int)(r >> 20);
    off = r & ((1LL << 20) - 1);
    src = (wsel == 0) ? wq : (wsel == 1) ? wk : (wsel == 2) ? wv : wo;
    dst = Wbase + ((long long)wsel << 20);
  }
  const float4* p = (const float4*)(src + off);
  float4 a = p[0], b = p[1];
  u16x8 o;
  o[0] = f2bf(a.x); o[1] = f2bf(a.y); o[2] = f2bf(a.z); o[3] = f2bf(a.w);
  o[4] = f2bf(b.x); o[5] = f2bf(b.y); o[6] = f2bf(b.z); o[7] = f2bf(b.w);
  *(u16x8*)(dst + off) = o;
}

// ---------------- bt-GEMM: C[M,N] = A[M,K] @ Bw[N,K]^T ----------------------
// MODE 1: f32 out + bias (N=1024). MODE 3: fused QKV (N=3072): cols 0..1023
// -> Q row-major, 1024..2047 -> K row-major, 2048..3071 -> V transposed to
// Vt[b*16+h][d][t]. Q/K/Vt are contiguous 8M-elem slots from Cout.
template <int MODE>
__global__ __launch_bounds__(256, 2)
void gemm_bt(const unsigned short* __restrict__ A,
             const unsigned short* __restrict__ Bw,
             void* __restrict__ Cout,
             const float* __restrict__ bias,
             int M, int N, int K) {
  __shared__ unsigned short As[128 * 32];
  __shared__ unsigned short Bs[128 * 32];
  const int tid = threadIdx.x;
  const int lane = tid & 63;
  const int w = tid >> 6;
  const int wr = w >> 1, wc = w & 1;                 // 2x2 wave grid
  const int row0 = blockIdx.y * 128;
  const int col0 = blockIdx.x * 128;
  const int lr = lane & 15;
  const int lk = (lane >> 4) * 8;

  f32x4 acc[4][4] = {};

  const int sr = tid >> 2;
  const int sc = (tid & 3) * 8;

  for (int k0 = 0; k0 < K; k0 += 32) {
    gl_lds16(A  + (size_t)(row0 + sr) * K + k0 + sc,      &As[sr * 32 + sc]);
    gl_lds16(A  + (size_t)(row0 + 64 + sr) * K + k0 + sc, &As[(64 + sr) * 32 + sc]);
    gl_lds16(Bw + (size_t)(col0 + sr) * K + k0 + sc,      &Bs[sr * 32 + sc]);
    gl_lds16(Bw + (size_t)(col0 + 64 + sr) * K + k0 + sc, &Bs[(64 + sr) * 32 + sc]);
    __syncthreads();

    bf8 a[4], b[4];
#pragma unroll
    for (int mi = 0; mi < 4; ++mi)
      a[mi] = *(const bf8*)&As[(wr * 64 + mi * 16 + lr) * 32 + lk];
#pragma unroll
    for (int ni = 0; ni < 4; ++ni)
      b[ni] = *(const bf8*)&Bs[(wc * 64 + ni * 16 + lr) * 32 + lk];
#pragma unroll
    for (int mi = 0; mi < 4; ++mi)
#pragma unroll
      for (int ni = 0; ni < 4; ++ni)
        acc[mi][ni] = __builtin_amdgcn_mfma_f32_16x16x32_bf16(
            a[mi], b[ni], acc[mi][ni], 0, 0, 0);
    __syncthreads();
  }

  // C/D layout: col=lane&15, row=(lane>>4)*4+r  [measured m89/m91]
#pragma unroll
  for (int mi = 0; mi < 4; ++mi) {
#pragma unroll
    for (int ni = 0; ni < 4; ++ni) {
      const int col = col0 + wc * 64 + ni * 16 + lr;
      const int rowb = row0 + wr * 64 + mi * 16 + (lane >> 4) * 4;
      if (MODE == 1) {
#pragma unroll
        for (int r = 0; r < 4; ++r)
          ((float*)Cout)[(size_t)(rowb + r) * N + col] = acc[mi][ni][r] + bias[col];
      } else {  // MODE 3: fused QKV routing (col0 is block-uniform)
        unsigned short* outb = (unsigned short*)Cout;
        if (col < 2048) {
          unsigned short* dst = outb + (col < 1024 ? 0 : 8 * 1024 * 1024);
          const int c = col & 1023;
#pragma unroll
          for (int r = 0; r < 4; ++r)
            dst[(size_t)(rowb + r) * 1024 + c] = f2bf(acc[mi][ni][r]);
        } else {
          // Vt[(b*16+h)][d][t]: 4 consecutive t per lane -> packed 8B store
          const int c = col - 2048;
          const int bidx = rowb >> 11, t0 = rowb & 2047;
          const int hh = c >> 6, dd = c & 63;
          uint2 pk;
          pk.x = (unsigned)f2bf(acc[mi][ni][0]) | ((unsigned)f2bf(acc[mi][ni][1]) << 16);
          pk.y = (unsigned)f2bf(acc[mi][ni][2]) | ((unsigned)f2bf(acc[mi][ni][3]) << 16);
          size_t addr = (((size_t)(bidx * Hh + hh)) * Dd + dd) * (size_t)Tt + t0;
          *(uint2*)(outb + 16 * 1024 * 1024 + addr) = pk;
        }
      }
    }
  }
}

// -------- flash attention: 32x32 MFMA, P fully in-register (T12) ------------
// Q,K,O in [B,T,C]; V pre-transposed Vt[b*16+h][d=64][t=2048]. 8 waves x 32 q
// = 256 q rows/block. KV tile 64, double-buffered, one barrier/tile. K/Vt LDS
// XOR-swizzled via pre-swizzled global source (G21). Swapped QK^T with
// mfma_32x32x16: S^T[kv][q=lane&31]; lane holds 32 of 64 kv (hi=lane>>5
// selects kv bit2). Softmax: in-lane tree + one lane^32 shuffle; m/l/alpha
// per-lane scalars; exp2 domain + defer-max. P -> bf16 via v_cvt_pk_bf16_f32
// pairs + v_permlane32_swap_b32 under semantics vdst[32:63]<->vsrc[0:31]:
// swap(a=U[2ks], b=U[2ks+1]) gives a={hi0: own U[2ks], hi1: partner U[2ks+1]}
// = W[0:1] and b={hi0: partner U[2ks], hi1: own U[2ks+1]} = W[2:3].
// (Round-8 had the inverse orientation -> absmax 4e-2; this is the flip.)
// PV: O^T = mfma(Vt_frag, P_frag). No P LDS buffer at all (LDS = 32 KB).
__global__ __launch_bounds__(512, 4)
void flash_attn(const unsigned short* __restrict__ Q,
                const unsigned short* __restrict__ Km,
                const unsigned short* __restrict__ Vt,
                unsigned short* __restrict__ O) {
  __shared__ unsigned short Ks[2][KVB * 64];     // [kv][d], swizzled
  __shared__ unsigned short Vts[2][64 * KVB];    // [d][kv], swizzled

  const int tid = threadIdx.x;
  const int lane = tid & 63;
  const int w = tid >> 6;                     // 0..7
  const int bh = blockIdx.x;                  // 0..63
  const int qt = blockIdx.y;                  // 0..7
  const int b = bh >> 4, h = bh & 15;
  const size_t base = (size_t)b * Tt * Cc + (size_t)h * Dd;
  const size_t vtbase = (size_t)bh * Dd * Tt;
  const int r31 = lane & 31, hi = lane >> 5;
  const int qrow = qt * 256 + w * 32 + r31;   // this lane's q row
  const int sw = r31 & 7;                     // read-side swizzle key

  // chunk offsets (elems) for A-frag reads, statically indexed by ks
  int coh[4];
#pragma unroll
  for (int ks = 0; ks < 4; ++ks) coh[ks] = ((2 * ks + hi) ^ sw) * 8;

  // Q B-frags: lane holds Q[qrow][d = 16ks + 8hi + 0..7], scaled by QSCALE
  bf8 qb[4];
#pragma unroll
  for (int ks = 0; ks < 4; ++ks) {
    bf8 t = *(const bf8*)(Q + base + (size_t)qrow * Cc + ks * 16 + hi * 8);
#pragma unroll
    for (int i = 0; i < 8; ++i)
      qb[ks][i] = (short)f2bf(bf2f((unsigned short)t[i]) * QSCALE);
  }

  float m_r = -INFINITY, l_r = 0.f;   // per-lane scalars for q = qrow
  f32x16 o_acc[2];                    // O^T: d = 32dt + (reg&3)+8*(reg>>2)+4hi
#pragma unroll
  for (int dt = 0; dt < 2; ++dt) o_acc[dt] = (f32x16)0.0f;

  // staging: dest chunk tid (linear); source chunk ^= row&7 (G21)
  const int strow = tid >> 3;                 // 0..63
  const int stch = tid & 7;
  const unsigned short* ksrc = Km + base + (size_t)strow * Cc + ((stch ^ (strow & 7)) * 8);
  const unsigned short* vsrc = Vt + vtbase + (size_t)strow * Tt + ((stch ^ (strow & 7)) * 8);

  gl_lds16(ksrc, &Ks[0][tid * 8]);
  gl_lds16(vsrc, &Vts[0][tid * 8]);
  __syncthreads();

  for (int t = 0; t < NT; ++t) {
    const int cur = t & 1;
    if (t + 1 < NT) {
      const int kb = (t + 1) * KVB;
      gl_lds16(ksrc + (size_t)kb * Cc, &Ks[cur ^ 1][tid * 8]);
      gl_lds16(vsrc + kb,              &Vts[cur ^ 1][tid * 8]);
    }

    // S^T[64kv][32q] = K[64kv x 64d] @ Q^T[64d x 32q], 2 mt x 4 ks chain
    f32x16 s[2];
#pragma unroll
    for (int mt = 0; mt < 2; ++mt) {
      f32x16 z = (f32x16)0.0f;
#pragma unroll
      for (int ks = 0; ks < 4; ++ks) {
        bf8 kf = *(const bf8*)&Ks[cur][(mt * 32 + r31) * 64 + coh[ks]];
        z = __builtin_amdgcn_mfma_f32_32x32x16_bf16(kf, qb[ks], z, 0, 0, 0);
      }
      s[mt] = z;
    }
    // lane holds S^T[kv][q=qrow]: kv = 32mt + (reg&3) + 8*(reg>>2) + 4hi

    // row max: tree over 32 in-lane + partner (lane^32) combine
    float a8[8];
#pragma unroll
    for (int mt = 0; mt < 2; ++mt)
#pragma unroll
      for (int g = 0; g < 4; ++g)
        a8[mt * 4 + g] = fmaxf(fmaxf(s[mt][4 * g], s[mt][4 * g + 1]),
                               fmaxf(s[mt][4 * g + 2], s[mt][4 * g + 3]));
    float mx = fmaxf(fmaxf(fmaxf(a8[0], a8[1]), fmaxf(a8[2], a8[3])),
                     fmaxf(fmaxf(a8[4], a8[5]), fmaxf(a8[6], a8[7])));
    mx = fmaxf(mx, __shfl_xor(mx, 32));

    // defer-max (T13): rescale only when some row grew by > 8 (log2 units)
    if (__any(mx > m_r + 8.0f)) {
      float mn = fmaxf(m_r, mx);
      float alpha = fexp2(m_r - mn);   // 0 on first tile
      m_r = mn;
      l_r *= alpha;
#pragma unroll
      for (int dt = 0; dt < 2; ++dt)
#pragma unroll
        for (int j = 0; j < 16; ++j) o_acc[dt][j] *= alpha;
    }

    // P = exp2(S - m) in place
#pragma unroll
    for (int mt = 0; mt < 2; ++mt)
#pragma unroll
      for (int j = 0; j < 16; ++j) s[mt][j] = fexp2(s[mt][j] - m_r);

    // row sum: 4-way partials + partner combine
    float q0 = 0.f, q1 = 0.f, q2 = 0.f, q3 = 0.f;
#pragma unroll
    for (int mt = 0; mt < 2; ++mt)
#pragma unroll
      for (int j = 0; j < 16; j += 4) {
        q0 += s[mt][j]; q1 += s[mt][j + 1]; q2 += s[mt][j + 2]; q3 += s[mt][j + 3];
      }
    float ps = (q0 + q1) + (q2 + q3);
    ps += __shfl_xor(ps, 32);
    l_r += ps;

    // pack P: group k -> 2 u32 (kv base 32(k>>2)+8(k&3)+4hi)
    unsigned U[8][2];
#pragma unroll
    for (int k = 0; k < 8; ++k) {
      U[k][0] = cvtpk(s[k >> 2][4 * (k & 3)],     s[k >> 2][4 * (k & 3) + 1]);
      U[k][1] = cvtpk(s[k >> 2][4 * (k & 3) + 2], s[k >> 2][4 * (k & 3) + 3]);
    }
    // B-frag pb[ks] (kv = 16ks + 8hi + e): FLIPPED orientation vs round 8.
    // swap(a=U[2ks], b=U[2ks+1]) -> a = W[0:1] source, b = W[2:3] source.
    bf8 pb[4];
#pragma unroll
    for (int ks = 0; ks < 4; ++ks) {
      unsigned a0 = U[2 * ks][0], b0 = U[2 * ks + 1][0];
      asm volatile("v_permlane32_swap_b32 %0, %1" : "+v"(a0), "+v"(b0));
      unsigned a1 = U[2 * ks][1], b1 = U[2 * ks + 1][1];
      asm volatile("v_permlane32_swap_b32 %0, %1" : "+v"(a1), "+v"(b1));
      union { unsigned u[4]; bf8 v; } pk_;
      pk_.u[0] = a0; pk_.u[1] = a1; pk_.u[2] = b0; pk_.u[3] = b1;
      pb[ks] = pk_.v;
    }

    // PV: O^T[64d][32q] += Vt[64d x 64kv] @ P^T[64kv x 32q]
#pragma unroll
    for (int dt = 0; dt < 2; ++dt) {
      f32x16 z = o_acc[dt];
#pragma unroll
      for (int ks = 0; ks < 4; ++ks) {
        bf8 vf = *(const bf8*)&Vts[cur][(dt * 32 + r31) * 64 + coh[ks]];
        z = __builtin_amdgcn_mfma_f32_32x32x16_bf16(vf, pb[ks], z, 0, 0, 0);
      }
      o_acc[dt] = z;
    }
    __syncthreads();   // all waves done with cur; prefetch drained
  }

  // epilogue: normalize, packed 8B stores; d = 32dt + 8g + 4hi + (0..3)
  const float linv = 1.0f / l_r;
#pragma unroll
  for (int dt = 0; dt < 2; ++dt)
#pragma unroll
    for (int g = 0; g < 4; ++g) {
      uint2 pk;
      pk.x = (unsigned)f2bf(o_acc[dt][4 * g] * linv) |
             ((unsigned)f2bf(o_acc[dt][4 * g + 1] * linv) << 16);
      pk.y = (unsigned)f2bf(o_acc[dt][4 * g + 2] * linv) |
             ((unsigned)f2bf(o_acc[dt][4 * g + 3] * linv) << 16);
      *(uint2*)(O + base + (size_t)qrow * Cc + dt * 32 + g * 8 + hi * 4) = pk;
    }
}

// ---------------- host launcher --------------------------------------------
extern "C" void kernel_launch(void* const* d_in, const int* in_sizes, int n_in,
                              void* d_out, int out_size, void* d_ws, size_t ws_size,
                              hipStream_t stream) {
  (void)in_sizes; (void)n_in; (void)out_size; (void)ws_size;
  const float* hs = (const float*)d_in[0];
  const float* wq = (const float*)d_in[1];
  const float* wk = (const float*)d_in[2];
  const float* wv = (const float*)d_in[3];
  const float* wo = (const float*)d_in[4];
  const float* bo = (const float*)d_in[5];

  // workspace layout (bf16), 72 MB. Xb dead after QKV proj -> attn out reuses it.
  char* ws = (char*)d_ws;
  const size_t MB = 1u << 20;
  unsigned short* Xb  = (unsigned short*)(ws + 0);        // 16 MB (later: attn out)
  unsigned short* Wqb = (unsigned short*)(ws + 16 * MB);  // Wq|Wk|Wv|Wo contiguous
  unsigned short* Wob = (unsigned short*)(ws + 22 * MB);
  unsigned short* Qb  = (unsigned short*)(ws + 24 * MB);  // Q|K|Vt contiguous 8M slots
  unsigned short* Kb  = (unsigned short*)(ws + 40 * MB);
  unsigned short* Vtb = (unsigned short*)(ws + 56 * MB);
  unsigned short* Ob  = Xb;

  // 1) fused cast: hs + 4 weights (12M elems / 8 per thread)
  cast_all<<<6144, 256, 0, stream>>>(hs, wq, wk, wv, wo, Xb, Wqb);

  // 2) fused QKV projection: N = 3072, epilogue routes Q/K/Vt
  gemm_bt<3><<<dim3(24, 64), 256, 0, stream>>>(Xb, Wqb, Qb, nullptr, Mm, 3072, Cc);

  // 3) attention
  flash_attn<<<dim3(Bb * Hh, Tt / 256), 512, 0, stream>>>(Qb, Kb, Vtb, Ob);

  // 4) output projection + bias (f32 out)
  gemm_bt<1><<<dim3(8, 64), 256, 0, stream>>>(Ob, Wob, (float*)d_out, bo, Mm, Cc, Cc);
}

// Round 11
// 197.716 us; speedup vs baseline: 2.7190x; 1.0088x over previous
//
#include <hip/hip_runtime.h>
#include <hip/hip_bf16.h>
#include <stdint.h>
#include <math.h>

// Problem constants
#define Bb 4
#define Tt 2048
#define Cc 1024
#define Hh 16
#define Dd 64
#define Mm (Bb * Tt)   // 8192 rows
#define KVB 64
#define NT (Tt / KVB)  // 32 kv tiles

typedef __attribute__((ext_vector_type(8))) short bf8;     // 8 x bf16, MFMA A/B frag
typedef __attribute__((ext_vector_type(4))) float f32x4;   // 16x16 C/D frag
typedef __attribute__((ext_vector_type(16))) float f32x16; // 32x32 C/D frag
typedef __attribute__((ext_vector_type(8))) float f32x8v;
typedef __attribute__((ext_vector_type(2))) float f32x2v;
typedef __attribute__((ext_vector_type(8))) unsigned short u16x8;

// log2(e)/8: folds the 1/sqrt(D) scale and exp->exp2 conversion into Q
#define QSCALE 0.1803368801111244f

__device__ __forceinline__ unsigned short f2bf(float f) {
  __hip_bfloat16 h = __float2bfloat16(f);   // native v_cvt, RNE
  return *reinterpret_cast<unsigned short*>(&h);
}
__device__ __forceinline__ float bf2f(unsigned short s) {
  union { unsigned u; float f; } v; v.u = ((unsigned)s) << 16;
  return v.f;
}
__device__ __forceinline__ float fexp2(float x) {
#if __has_builtin(__builtin_amdgcn_exp2f)
  return __builtin_amdgcn_exp2f(x);
#else
  return exp2f(x);
#endif
}
__device__ __forceinline__ float fmax3(float a, float b, float c) {
  float r;
  asm("v_max3_f32 %0, %1, %2, %3" : "=v"(r) : "v"(a), "v"(b), "v"(c));
  return r;
}
__device__ __forceinline__ unsigned cvtpk(float lo, float hi) {
  unsigned r;
  asm volatile("v_cvt_pk_bf16_f32 %0, %1, %2" : "=v"(r) : "v"(lo), "v"(hi));
  return r;
}
__device__ __forceinline__ void gl_lds16(const void* g, void* l) {
  __builtin_amdgcn_global_load_lds(
      (const __attribute__((address_space(1))) void*)g,
      (__attribute__((address_space(3))) void*)l, 16, 0, 0);
}

// ------------- fused fp32 -> bf16 cast: hs + 4 weights, one launch ----------
__global__ __launch_bounds__(256) void cast_all(
    const float* __restrict__ hs, const float* __restrict__ wq,
    const float* __restrict__ wk, const float* __restrict__ wv,
    const float* __restrict__ wo, unsigned short* __restrict__ Xb,
    unsigned short* __restrict__ Wbase) {
  long long g = (long long)(blockIdx.x * 256 + threadIdx.x) * 8;
  const float* src;
  unsigned short* dst;
  long long off;
  const long long HS = 8LL * 1024 * 1024;
  if (g < HS) {
    src = hs; dst = Xb; off = g;
  } else {
    long long r = g - HS;
    int wsel = (int)(r >> 20);
    off = r & ((1LL << 20) - 1);
    src = (wsel == 0) ? wq : (wsel == 1) ? wk : (wsel == 2) ? wv : wo;
    dst = Wbase + ((long long)wsel << 20);
  }
  const float4* p = (const float4*)(src + off);
  float4 a = p[0], b = p[1];
  u16x8 o;
  o[0] = f2bf(a.x); o[1] = f2bf(a.y); o[2] = f2bf(a.z); o[3] = f2bf(a.w);
  o[4] = f2bf(b.x); o[5] = f2bf(b.y); o[6] = f2bf(b.z); o[7] = f2bf(b.w);
  *(u16x8*)(dst + off) = o;
}

// ---------------- bt-GEMM: C[M,N] = A[M,K] @ Bw[N,K]^T ----------------------
// MODE 1: f32 out + bias (N=1024). MODE 3: fused QKV (N=3072): cols 0..1023
// -> Q row-major, 1024..2047 -> K row-major, 2048..3071 -> V transposed to
// Vt[b*16+h][d][t]. Q/K/Vt are contiguous 8M-elem slots from Cout.
// XCD note: nx (24 / 8) = 0 mod 8 -> all blocks sharing a B panel (same bx)
// already land on one XCD under round-robin dispatch; no swizzle needed.
template <int MODE>
__global__ __launch_bounds__(256, 2)
void gemm_bt(const unsigned short* __restrict__ A,
             const unsigned short* __restrict__ Bw,
             void* __restrict__ Cout,
             const float* __restrict__ bias,
             int M, int N, int K) {
  __shared__ unsigned short As[128 * 32];
  __shared__ unsigned short Bs[128 * 32];
  const int tid = threadIdx.x;
  const int lane = tid & 63;
  const int w = tid >> 6;
  const int wr = w >> 1, wc = w & 1;                 // 2x2 wave grid
  const int row0 = blockIdx.y * 128;
  const int col0 = blockIdx.x * 128;
  const int lr = lane & 15;
  const int lk = (lane >> 4) * 8;

  f32x4 acc[4][4] = {};

  const int sr = tid >> 2;
  const int sc = (tid & 3) * 8;

  for (int k0 = 0; k0 < K; k0 += 32) {
    gl_lds16(A  + (size_t)(row0 + sr) * K + k0 + sc,      &As[sr * 32 + sc]);
    gl_lds16(A  + (size_t)(row0 + 64 + sr) * K + k0 + sc, &As[(64 + sr) * 32 + sc]);
    gl_lds16(Bw + (size_t)(col0 + sr) * K + k0 + sc,      &Bs[sr * 32 + sc]);
    gl_lds16(Bw + (size_t)(col0 + 64 + sr) * K + k0 + sc, &Bs[(64 + sr) * 32 + sc]);
    __syncthreads();

    bf8 a[4], b[4];
#pragma unroll
    for (int mi = 0; mi < 4; ++mi)
      a[mi] = *(const bf8*)&As[(wr * 64 + mi * 16 + lr) * 32 + lk];
#pragma unroll
    for (int ni = 0; ni < 4; ++ni)
      b[ni] = *(const bf8*)&Bs[(wc * 64 + ni * 16 + lr) * 32 + lk];
#pragma unroll
    for (int mi = 0; mi < 4; ++mi)
#pragma unroll
      for (int ni = 0; ni < 4; ++ni)
        acc[mi][ni] = __builtin_amdgcn_mfma_f32_16x16x32_bf16(
            a[mi], b[ni], acc[mi][ni], 0, 0, 0);
    __syncthreads();
  }

  // C/D layout: col=lane&15, row=(lane>>4)*4+r  [measured m89/m91]
#pragma unroll
  for (int mi = 0; mi < 4; ++mi) {
#pragma unroll
    for (int ni = 0; ni < 4; ++ni) {
      const int col = col0 + wc * 64 + ni * 16 + lr;
      const int rowb = row0 + wr * 64 + mi * 16 + (lane >> 4) * 4;
      if (MODE == 1) {
#pragma unroll
        for (int r = 0; r < 4; ++r)
          ((float*)Cout)[(size_t)(rowb + r) * N + col] = acc[mi][ni][r] + bias[col];
      } else {  // MODE 3: fused QKV routing (col0 is block-uniform)
        unsigned short* outb = (unsigned short*)Cout;
        if (col < 2048) {
          unsigned short* dst = outb + (col < 1024 ? 0 : 8 * 1024 * 1024);
          const int c = col & 1023;
#pragma unroll
          for (int r = 0; r < 4; ++r)
            dst[(size_t)(rowb + r) * 1024 + c] = f2bf(acc[mi][ni][r]);
        } else {
          // Vt[(b*16+h)][d][t]: 4 consecutive t per lane -> packed 8B store
          const int c = col - 2048;
          const int bidx = rowb >> 11, t0 = rowb & 2047;
          const int hh = c >> 6, dd = c & 63;
          uint2 pk;
          pk.x = (unsigned)f2bf(acc[mi][ni][0]) | ((unsigned)f2bf(acc[mi][ni][1]) << 16);
          pk.y = (unsigned)f2bf(acc[mi][ni][2]) | ((unsigned)f2bf(acc[mi][ni][3]) << 16);
          size_t addr = (((size_t)(bidx * Hh + hh)) * Dd + dd) * (size_t)Tt + t0;
          *(uint2*)(outb + 16 * 1024 * 1024 + addr) = pk;
        }
      }
    }
  }
}

// -------- flash attention: 32x32 MFMA, P fully in-register (T12) ------------
// Same structure as round 10 (verified, absmax 3.05e-4); this round trims the
// VALU stream: v_max3_f32 tree (31 fmax -> 17 ops), vector-form subtract /
// sum tree (v_pk_add_f32 candidates), vectorized rescale + epilogue.
__global__ __launch_bounds__(512, 4)
void flash_attn(const unsigned short* __restrict__ Q,
                const unsigned short* __restrict__ Km,
                const unsigned short* __restrict__ Vt,
                unsigned short* __restrict__ O) {
  __shared__ unsigned short Ks[2][KVB * 64];     // [kv][d], swizzled
  __shared__ unsigned short Vts[2][64 * KVB];    // [d][kv], swizzled

  const int tid = threadIdx.x;
  const int lane = tid & 63;
  const int w = tid >> 6;                     // 0..7
  const int bh = blockIdx.x;                  // 0..63
  const int qt = blockIdx.y;                  // 0..7
  const int b = bh >> 4, h = bh & 15;
  const size_t base = (size_t)b * Tt * Cc + (size_t)h * Dd;
  const size_t vtbase = (size_t)bh * Dd * Tt;
  const int r31 = lane & 31, hi = lane >> 5;
  const int qrow = qt * 256 + w * 32 + r31;   // this lane's q row
  const int sw = r31 & 7;                     // read-side swizzle key

  // chunk offsets (elems) for A-frag reads, statically indexed by ks
  int coh[4];
#pragma unroll
  for (int ks = 0; ks < 4; ++ks) coh[ks] = ((2 * ks + hi) ^ sw) * 8;

  // Q B-frags: lane holds Q[qrow][d = 16ks + 8hi + 0..7], scaled by QSCALE
  bf8 qb[4];
#pragma unroll
  for (int ks = 0; ks < 4; ++ks) {
    bf8 t = *(const bf8*)(Q + base + (size_t)qrow * Cc + ks * 16 + hi * 8);
#pragma unroll
    for (int i = 0; i < 8; ++i)
      qb[ks][i] = (short)f2bf(bf2f((unsigned short)t[i]) * QSCALE);
  }

  float m_r = -INFINITY, l_r = 0.f;   // per-lane scalars for q = qrow
  f32x16 o_acc[2];                    // O^T: d = 32dt + (reg&3)+8*(reg>>2)+4hi
#pragma unroll
  for (int dt = 0; dt < 2; ++dt) o_acc[dt] = (f32x16)0.0f;

  // staging: dest chunk tid (linear); source chunk ^= row&7 (G21)
  const int strow = tid >> 3;                 // 0..63
  const int stch = tid & 7;
  const unsigned short* ksrc = Km + base + (size_t)strow * Cc + ((stch ^ (strow & 7)) * 8);
  const unsigned short* vsrc = Vt + vtbase + (size_t)strow * Tt + ((stch ^ (strow & 7)) * 8);

  gl_lds16(ksrc, &Ks[0][tid * 8]);
  gl_lds16(vsrc, &Vts[0][tid * 8]);
  __syncthreads();

  for (int t = 0; t < NT; ++t) {
    const int cur = t & 1;
    if (t + 1 < NT) {
      const int kb = (t + 1) * KVB;
      gl_lds16(ksrc + (size_t)kb * Cc, &Ks[cur ^ 1][tid * 8]);
      gl_lds16(vsrc + kb,              &Vts[cur ^ 1][tid * 8]);
    }

    // S^T[64kv][32q] = K[64kv x 64d] @ Q^T[64d x 32q], 2 mt x 4 ks chain
    f32x16 s0, s1;
    {
      f32x16 z = (f32x16)0.0f;
#pragma unroll
      for (int ks = 0; ks < 4; ++ks) {
        bf8 kf = *(const bf8*)&Ks[cur][(r31) * 64 + coh[ks]];
        z = __builtin_amdgcn_mfma_f32_32x32x16_bf16(kf, qb[ks], z, 0, 0, 0);
      }
      s0 = z;
      z = (f32x16)0.0f;
#pragma unroll
      for (int ks = 0; ks < 4; ++ks) {
        bf8 kf = *(const bf8*)&Ks[cur][(32 + r31) * 64 + coh[ks]];
        z = __builtin_amdgcn_mfma_f32_32x32x16_bf16(kf, qb[ks], z, 0, 0, 0);
      }
      s1 = z;
    }
    // lane holds S^T[kv][q=qrow]: kv = 32mt + (reg&3) + 8*(reg>>2) + 4hi

    // row max: max3 tree over 32 in-lane (17 ops) + partner combine
    float t0 = fmax3(s0[0], s0[1], s0[2]);
    float t1 = fmax3(s0[3], s0[4], s0[5]);
    float t2 = fmax3(s0[6], s0[7], s0[8]);
    float t3 = fmax3(s0[9], s0[10], s0[11]);
    float t4 = fmax3(s0[12], s0[13], s0[14]);
    float t5 = fmax3(s0[15], s1[0], s1[1]);
    float t6 = fmax3(s1[2], s1[3], s1[4]);
    float t7 = fmax3(s1[5], s1[6], s1[7]);
    float t8 = fmax3(s1[8], s1[9], s1[10]);
    float t9 = fmax3(s1[11], s1[12], s1[13]);
    float t10 = fmaxf(s1[14], s1[15]);
    float u0 = fmax3(t0, t1, t2);
    float u1 = fmax3(t3, t4, t5);
    float u2 = fmax3(t6, t7, t8);
    float u3 = fmaxf(t9, t10);
    float mx = fmaxf(fmax3(u0, u1, u2), u3);
    mx = fmaxf(mx, __shfl_xor(mx, 32));

    // defer-max (T13): rescale only when some row grew by > 8 (log2 units)
    if (__any(mx > m_r + 8.0f)) {
      float mn = fmaxf(m_r, mx);
      float alpha = fexp2(m_r - mn);   // 0 on first tile
      m_r = mn;
      l_r *= alpha;
      o_acc[0] *= alpha;
      o_acc[1] *= alpha;
    }

    // P = exp2(S - m): vector subtract (pk-add candidates), scalar exp2
    s0 = s0 - m_r;
    s1 = s1 - m_r;
#pragma unroll
    for (int j = 0; j < 16; ++j) { s0[j] = fexp2(s0[j]); s1[j] = fexp2(s1[j]); }

    // row sum: vector halving tree + partner combine
    {
      f32x16 t16 = s0 + s1;
      f32x8v t8v = __builtin_shufflevector(t16, t16, 0, 1, 2, 3, 4, 5, 6, 7) +
                   __builtin_shufflevector(t16, t16, 8, 9, 10, 11, 12, 13, 14, 15);
      f32x4 t4v = __builtin_shufflevector(t8v, t8v, 0, 1, 2, 3) +
                  __builtin_shufflevector(t8v, t8v, 4, 5, 6, 7);
      f32x2v t2v = __builtin_shufflevector(t4v, t4v, 0, 1) +
                   __builtin_shufflevector(t4v, t4v, 2, 3);
      float ps = t2v[0] + t2v[1];
      ps += __shfl_xor(ps, 32);
      l_r += ps;
    }

    // pack P: group k -> 2 u32 (kv base 32(k>>2)+8(k&3)+4hi); k<4 from s0
    unsigned U[8][2];
#pragma unroll
    for (int k = 0; k < 4; ++k) {
      U[k][0] = cvtpk(s0[4 * k],     s0[4 * k + 1]);
      U[k][1] = cvtpk(s0[4 * k + 2], s0[4 * k + 3]);
    }
#pragma unroll
    for (int k = 0; k < 4; ++k) {
      U[4 + k][0] = cvtpk(s1[4 * k],     s1[4 * k + 1]);
      U[4 + k][1] = cvtpk(s1[4 * k + 2], s1[4 * k + 3]);
    }
    // B-frag pb[ks] (kv = 16ks + 8hi + e), S1 swap semantics (verified r10):
    // swap(a=U[2ks], b=U[2ks+1]) -> a = W[0:1] source, b = W[2:3] source.
    bf8 pb[4];
#pragma unroll
    for (int ks = 0; ks < 4; ++ks) {
      unsigned a0 = U[2 * ks][0], b0 = U[2 * ks + 1][0];
      asm volatile("v_permlane32_swap_b32 %0, %1" : "+v"(a0), "+v"(b0));
      unsigned a1 = U[2 * ks][1], b1 = U[2 * ks + 1][1];
      asm volatile("v_permlane32_swap_b32 %0, %1" : "+v"(a1), "+v"(b1));
      union { unsigned u[4]; bf8 v; } pk_;
      pk_.u[0] = a0; pk_.u[1] = a1; pk_.u[2] = b0; pk_.u[3] = b1;
      pb[ks] = pk_.v;
    }

    // PV: O^T[64d][32q] += Vt[64d x 64kv] @ P^T[64kv x 32q]
#pragma unroll
    for (int dt = 0; dt < 2; ++dt) {
      f32x16 z = o_acc[dt];
#pragma unroll
      for (int ks = 0; ks < 4; ++ks) {
        bf8 vf = *(const bf8*)&Vts[cur][(dt * 32 + r31) * 64 + coh[ks]];
        z = __builtin_amdgcn_mfma_f32_32x32x16_bf16(vf, pb[ks], z, 0, 0, 0);
      }
      o_acc[dt] = z;
    }
    __syncthreads();   // all waves done with cur; prefetch drained
  }

  // epilogue: normalize (vector mul), packed 8B stores; d = 32dt+8g+4hi+(0..3)
  const float linv = 1.0f / l_r;
#pragma unroll
  for (int dt = 0; dt < 2; ++dt) {
    f32x16 on = o_acc[dt] * linv;
#pragma unroll
    for (int g = 0; g < 4; ++g) {
      uint2 pk;
      pk.x = (unsigned)f2bf(on[4 * g]) | ((unsigned)f2bf(on[4 * g + 1]) << 16);
      pk.y = (unsigned)f2bf(on[4 * g + 2]) | ((unsigned)f2bf(on[4 * g + 3]) << 16);
      *(uint2*)(O + base + (size_t)qrow * Cc + dt * 32 + g * 8 + hi * 4) = pk;
    }
  }
}

// ---------------- host launcher --------------------------------------------
extern "C" void kernel_launch(void* const* d_in, const int* in_sizes, int n_in,
                              void* d_out, int out_size, void* d_ws, size_t ws_size,
                              hipStream_t stream) {
  (void)in_sizes; (void)n_in; (void)out_size; (void)ws_size;
  const float* hs = (const float*)d_in[0];
  const float* wq = (const float*)d_in[1];
  const float* wk = (const float*)d_in[2];
  const float* wv = (const float*)d_in[3];
  const float* wo = (const float*)d_in[4];
  const float* bo = (const float*)d_in[5];

  // workspace layout (bf16), 72 MB. Xb dead after QKV proj -> attn out reuses it.
  char* ws = (char*)d_ws;
  const size_t MB = 1u << 20;
  unsigned short* Xb  = (unsigned short*)(ws + 0);        // 16 MB (later: attn out)
  unsigned short* Wqb = (unsigned short*)(ws + 16 * MB);  // Wq|Wk|Wv|Wo contiguous
  unsigned short* Wob = (unsigned short*)(ws + 22 * MB);
  unsigned short* Qb  = (unsigned short*)(ws + 24 * MB);  // Q|K|Vt contiguous 8M slots
  unsigned short* Kb  = (unsigned short*)(ws + 40 * MB);
  unsigned short* Vtb = (unsigned short*)(ws + 56 * MB);
  unsigned short* Ob  = Xb;

  // 1) fused cast: hs + 4 weights (12M elems / 8 per thread)
  cast_all<<<6144, 256, 0, stream>>>(hs, wq, wk, wv, wo, Xb, Wqb);

  // 2) fused QKV projection: N = 3072, epilogue routes Q/K/Vt
  gemm_bt<3><<<dim3(24, 64), 256, 0, stream>>>(Xb, Wqb, Qb, nullptr, Mm, 3072, Cc);

  // 3) attention
  flash_attn<<<dim3(Bb * Hh, Tt / 256), 512, 0, stream>>>(Qb, Kb, Vtb, Ob);

  // 4) output projection + bias (f32 out)
  gemm_bt<1><<<dim3(8, 64), 256, 0, stream>>>(Ob, Wob, (float*)d_out, bo, Mm, Cc, Cc);
}